// Round 1
// 380.819 us; speedup vs baseline: 1.1175x; 1.1175x over previous
//
#include <hip/hip_runtime.h>
#include <math.h>

// ---------------------------------------------------------------------------
// VQVAEZMultiScale round 5 — DMA-staged MFMA match.
//   Round-4 diagnosis: match_bulk was VALU-bound (VALUBusy 40% vs MfmaUtil
//   15.5%) on in-loop f32->bf16 splitting (redone 4x per rowtile) plus 10%
//   LDS bank-conflict overhead from misaligned padded tiles.
//   Changes:
//     * encode_all now also writes bf16 hi/lo planes of feat, K-tiled
//       [rowblk][kc][128][32] and XOR-swizzled (q ^= row&3), into d_out
//       scratch (out is fully rewritten by fuse1/fuse2 afterwards).
//     * split_cb writes cbs in the same tiled+swizzled layout.
//     * match_bulk stages A0/A1/B0/B1 via global_load_lds width=16 (no VALU
//       conversion, no ds_write, contiguous 1 KiB per wave-instruction);
//       fragment ds_read_b128 are 16B-aligned and conflict-free via the
//       swizzle. LDS 40 KB -> 32 KB. Bijective XCD swizzle groups the 4
//       codeblk blocks of each rowtile on one XCD L2.
//     * expf -> __expf in prob partial sums (close calls are deferred to
//       fp64 anyway).
// Workspace layout (float units), total ~57.7 MB (unchanged):
//   feat   [43008][256] f32        @ 0
//   partials [75776][8] float4     @ 11010048
//   prob   f32[43008]              @ 13434880
//   idx1   int[43008]              @ 13477888
//   idx2   int[32768]              @ 13520896
//   cnf    f32[1024]               @ 13553664
//   cnd    double[1024]            @ 13554688
//   cbs    bf16 tiled [book][split][codeblk][kc][128][32] @ 13556736
//   img1   [8][3][128][128]        @ 13818880
//   img2   [8][3][64][64]          @ 14212096
//   rlist  int[75776]              @ 14310400
//   dlist  int[32768]              @ 14386176
//   cnt    int[2]                  @ 14418944
// d_out scratch reuse (before fuse1): bf16 feat planes
//   [split][336 rowblk][8 kc][128][32] ushort, 22,020,096 ushorts = 44 MB.
// Output: out0 @0, zidx @8388608 (as float), ste0 @8454144 (all f32, NCHW)
// ---------------------------------------------------------------------------

#define FEAT_OFF   0
#define PART_OFF   11010048
#define PROB_OFF   13434880
#define IDX1_OFF   13477888
#define IDX2_OFF   13520896
#define CNF_OFF    13553664
#define CND_OFF    13554688
#define CBS_OFF    13556736
#define IMG1_OFF   13818880
#define IMG2_OFF   14212096
#define RLIST_OFF  14310400
#define DLIST_OFF  14386176
#define CNT_OFF    14418944

#define PLANE_STRIDE 11010048   // ushorts per split plane (336*8*128*32)

#define EPS_V 1e-3f          // v abs error <= ~3e-5 worst-case -> 30x margin
#define EPS_P_REL 2e-3f      // prob rel error <= ~1e-4 -> 20x margin

typedef __attribute__((ext_vector_type(8))) short short8;
typedef __attribute__((ext_vector_type(4))) float f32x4;

__device__ inline unsigned short f2bf(float x) {
    unsigned u = __float_as_uint(x);
    return (unsigned short)((u + 0x7FFFu + ((u >> 16) & 1u)) >> 16);
}
__device__ inline float bf2f(unsigned short h) {
    return __uint_as_float(((unsigned)h) << 16);
}

// global -> LDS direct copy, 16 B per lane. LDS dest must be wave-uniform.
__device__ inline void glds16(const unsigned short* g, unsigned short* l) {
    __builtin_amdgcn_global_load_lds(
        (const __attribute__((address_space(1))) void*)g,
        (__attribute__((address_space(3))) void*)l, 16, 0, 0);
}

__global__ void zero_cnt(int* cnt) { if (threadIdx.x < 2) cnt[threadIdx.x] = 0; }

// ---- bilinear downsample (reference order: H-average first, then W)
__global__ void ds_kernel(const float* __restrict__ img, float* __restrict__ out,
                          int Hout, int Wout, int o, int f) {
    int i = blockIdx.x * blockDim.x + threadIdx.x;
    if (i >= 8 * 3 * Hout * Wout) return;
    int x = i % Wout;
    int t = i / Wout;
    int y = t % Hout;
    int bc = t / Hout;
    const float* base = img + ((size_t)bc * 256 + (size_t)(y * f + o)) * 256;
    int cx = x * f + o;
    float v00 = base[cx],     v10 = base[256 + cx];
    float v01 = base[cx + 1], v11 = base[256 + cx + 1];
    out[i] = ((v00 + v10) * 0.5f + (v01 + v11) * 0.5f) * 0.5f;
}

// ---- per-code squared norms, fp64 + f32 copies
__global__ void cnorm_kernel(const float* __restrict__ cb, double* __restrict__ cnd,
                             float* __restrict__ cnf) {
    int row = blockIdx.x;                    // 0..1023
    const float* p = cb + (size_t)row * 256;
    int lane = threadIdx.x;                  // 64
    double s = 0.0;
    for (int c = lane; c < 256; c += 64) {
        double v = (double)p[c];
        s = fma(v, v, s);
    }
    #pragma unroll
    for (int off = 32; off; off >>= 1) s += __shfl_down(s, off);
    if (lane == 0) { cnd[row] = s; cnf[row] = (float)s; }
}

// ---- split both codebooks into bf16 hi/lo planes, tiled+swizzled layout:
//      cbs[book][split][codeblk][kc][row(128)][32] with q ^= row&3 within 32.
__global__ void split_cb(const float* __restrict__ codebooks, unsigned short* __restrict__ cbs) {
    int i = blockIdx.x * 256 + threadIdx.x;      // over 2*512*256 = 262144
    if (i >= 262144) return;
    int book = i >> 17, rem = i & 131071;        // rem = code*256 + ch
    int code = rem >> 8, ch = rem & 255;
    float c = codebooks[(size_t)book * 131072 + rem];
    unsigned short h0 = f2bf(c);
    unsigned short h1 = f2bf(c - bf2f(h0));
    int codeblk = code >> 7, row = code & 127;
    int kc = ch >> 5, q = (ch >> 3) & 3, j = ch & 7;
    int qs = q ^ (row & 3);
    size_t off = ((((size_t)(book * 2) * 4 + codeblk) * 8 + kc) * 128 + row) * 32 + qs * 8 + j;
    cbs[off] = h0;                               // split 0
    cbs[off + 4 * 32768] = h1;                   // split 1 (stride 4 codeblk tiles)
}

// ---- stride-4 patchify conv, all 3 scales in one launch.
//      Also emits bf16 hi/lo planes of feat in the tiled+swizzled layout.
__launch_bounds__(256)
__global__ void encode_all(const float* __restrict__ image,
                           const float* __restrict__ img1,
                           const float* __restrict__ img2,
                           const float* __restrict__ w,
                           const float* __restrict__ bias,
                           float* __restrict__ feat,
                           unsigned short* __restrict__ featbf) {
    __shared__ float patch[12 * 256];
    int bid = blockIdx.x;
    const float* img; int Hout, rowbase, local;
    if (bid < 512)      { img = image; Hout = 64; rowbase = 0;     local = bid; }
    else if (bid < 768) { img = img1;  Hout = 32; rowbase = 32768; local = bid - 512; }
    else                { img = img2;  Hout = 16; rowbase = 40960; local = bid - 768; }
    int Wout = Hout;
    int tid = threadIdx.x;
    int b = local / Hout, y = local % Hout;
    int Himg = Hout * 4, Wimg = Wout * 4;

    const float* ibase = img + (size_t)b * 3 * Himg * Wimg;
    int nload = 12 * Wimg;
    for (int i = tid; i < nload; i += 256) {
        int col = i % Wimg, r = i / Wimg;    // r = ci*4 + kh
        int ci = r >> 2, kh = r & 3;
        patch[r * Wimg + col] = ibase[((size_t)ci * Himg + 4 * y + kh) * Wimg + col];
    }
    float wr[48];
    #pragma unroll
    for (int j = 0; j < 48; j++) wr[j] = w[tid * 48 + j];
    float bv = bias[tid];
    __syncthreads();

    int kc = tid >> 5, qch = (tid >> 3) & 3, jch = tid & 7;
    int rb = rowbase + (b * Hout + y) * Wout;
    for (int x = 0; x < Wout; x++) {
        float acc = 0.f;
        #pragma unroll
        for (int ci = 0; ci < 3; ci++)
            #pragma unroll
            for (int kh = 0; kh < 4; kh++) {
                const float* pr = &patch[(ci * 4 + kh) * Wimg + 4 * x];
                #pragma unroll
                for (int kw = 0; kw < 4; kw++)
                    acc = fmaf(pr[kw], wr[ci * 16 + kh * 4 + kw], acc);
            }
        float val = acc + bv;
        int r = rb + x;
        feat[(size_t)r * 256 + tid] = val;
        unsigned short hi = f2bf(val);
        unsigned short lo = f2bf(val - bf2f(hi));
        int rowblk = r >> 7, rrow = r & 127;
        int qs = qch ^ (rrow & 3);
        size_t off = (((size_t)rowblk * 8 + kc) * 128 + rrow) * 32 + qs * 8 + jch;
        featbf[off] = hi;
        featbf[off + PLANE_STRIDE] = lo;
    }
}

// ---- bulk MFMA match. Block: 128 virtual-rows x 128 codes; grid 592x4.
//      DMA staging via global_load_lds, swizzled conflict-free fragment reads.
__launch_bounds__(256, 3)
__global__ void match_bulk(const unsigned short* __restrict__ featbf,
                           const unsigned short* __restrict__ cbs,
                           const float* __restrict__ cnf,
                           float* __restrict__ partials) {
    __shared__ unsigned short A0s[4096], A1s[4096], B0s[4096], B1s[4096];
    // bijective XCD swizzle: 2368 = 8*296; co-locate the 4 codeblk blocks of a
    // rowtile on one XCD L2 so the feat tile is fetched once, not 4x.
    int bid0 = blockIdx.x;
    int bid = (bid0 & 7) * 296 + (bid0 >> 3);
    int codeblk = bid & 3, rowtile = bid >> 2;     // 4 x 592
    int book = (rowtile >= 336) ? 1 : 0;
    int rowblk = book ? rowtile - 336 : rowtile;
    int vr0 = rowtile * 128;
    int tid = threadIdx.x;
    int wid = tid >> 6, l = tid & 63;
    int waveY = wid & 1, waveX = wid >> 1;
    int lm = l & 15, lq = l >> 4;
    int slot = lq ^ (lm & 3);                      // swizzled channel-quad
    int wlds = wid * 512;                          // ushort units, 1 KiB chunks

    f32x4 acc[4][4];
    #pragma unroll
    for (int rt = 0; rt < 4; rt++)
        #pragma unroll
        for (int ct = 0; ct < 4; ct++) acc[rt][ct] = (f32x4)0.0f;

    const unsigned short* gA0 = featbf + (size_t)rowblk * 32768 + tid * 8;
    const unsigned short* gA1 = gA0 + PLANE_STRIDE;
    const unsigned short* gB0 = cbs + ((size_t)(book * 8) + codeblk) * 32768 + tid * 8;
    const unsigned short* gB1 = gB0 + 4 * 32768;

    #pragma unroll
    for (int kc = 0; kc < 8; kc++) {
        const unsigned short* ga0 = gA0 + kc * 4096;
        const unsigned short* ga1 = gA1 + kc * 4096;
        const unsigned short* gb0 = gB0 + kc * 4096;
        const unsigned short* gb1 = gB1 + kc * 4096;
        #pragma unroll
        for (int i = 0; i < 2; i++) {
            glds16(ga0 + i * 2048, &A0s[i * 2048 + wlds]);
            glds16(ga1 + i * 2048, &A1s[i * 2048 + wlds]);
            glds16(gb0 + i * 2048, &B0s[i * 2048 + wlds]);
            glds16(gb1 + i * 2048, &B1s[i * 2048 + wlds]);
        }
        __syncthreads();
        short8 a0[4], a1[4], b0[4], b1[4];
        #pragma unroll
        for (int t = 0; t < 4; t++) {
            int ra = (waveY * 64 + t * 16 + lm) * 32 + slot * 8;
            int rbx = (waveX * 64 + t * 16 + lm) * 32 + slot * 8;
            a0[t] = *(const short8*)&A0s[ra];
            a1[t] = *(const short8*)&A1s[ra];
            b0[t] = *(const short8*)&B0s[rbx];
            b1[t] = *(const short8*)&B1s[rbx];
        }
        #pragma unroll
        for (int rt = 0; rt < 4; rt++)
            #pragma unroll
            for (int ct = 0; ct < 4; ct++) {
                acc[rt][ct] = __builtin_amdgcn_mfma_f32_16x16x32_bf16(a0[rt], b0[ct], acc[rt][ct], 0, 0, 0);
                acc[rt][ct] = __builtin_amdgcn_mfma_f32_16x16x32_bf16(a0[rt], b1[ct], acc[rt][ct], 0, 0, 0);
                acc[rt][ct] = __builtin_amdgcn_mfma_f32_16x16x32_bf16(a1[rt], b0[ct], acc[rt][ct], 0, 0, 0);
            }
        __syncthreads();
    }

    float cnv[4];
    #pragma unroll
    for (int ct = 0; ct < 4; ct++)
        cnv[ct] = cnf[book * 512 + codeblk * 128 + waveX * 64 + ct * 16 + lm];
    float4* part4 = (float4*)partials;

    #pragma unroll
    for (int rt = 0; rt < 4; rt++) {
        #pragma unroll
        for (int j = 0; j < 4; j++) {
            float v[4];
            #pragma unroll
            for (int ct = 0; ct < 4; ct++)
                v[ct] = 2.0f * acc[rt][ct][j] - cnv[ct];
            float m1 = v[0], m2 = -3.4e38f;
            int k1 = codeblk * 128 + waveX * 64 + 0 * 16 + lm;
            #pragma unroll
            for (int ct = 1; ct < 4; ct++) {
                int kk = codeblk * 128 + waveX * 64 + ct * 16 + lm;
                if (v[ct] > m1 || (v[ct] == m1 && kk < k1)) { m2 = m1; m1 = v[ct]; k1 = kk; }
                else m2 = fmaxf(m2, v[ct]);
            }
            #pragma unroll
            for (int off = 1; off < 16; off <<= 1) {
                float mo1 = __shfl_xor(m1, off);
                float mo2 = __shfl_xor(m2, off);
                int ko1 = __shfl_xor(k1, off);
                if (mo1 > m1 || (mo1 == m1 && ko1 < k1)) { m2 = fmaxf(m1, mo2); m1 = mo1; k1 = ko1; }
                else m2 = fmaxf(m2, mo1);
            }
            float s = 0.f;
            #pragma unroll
            for (int ct = 0; ct < 4; ct++) s += __expf(v[ct] - m1);
            #pragma unroll
            for (int off = 1; off < 16; off <<= 1) s += __shfl_xor(s, off);
            if (lm == 0) {
                int vr = vr0 + waveY * 64 + rt * 16 + lq * 4 + j;
                float4 st = make_float4(m1, m2, __int_as_float(k1), s);
                part4[(size_t)vr * 8 + codeblk * 2 + waveX] = st;
            }
        }
    }
}

// ---- combine the 8 per-slice partials of each row; write idx/prob; flag rescues
__global__ void combine_rows(const float* __restrict__ partials,
                             int* __restrict__ idx1, int* __restrict__ idx2,
                             float* __restrict__ prob,
                             int* __restrict__ rlist, int* __restrict__ cnt) {
    int vr = blockIdx.x * 256 + threadIdx.x;      // grid 296*256 = 75776 exact
    const float4* p = (const float4*)partials + (size_t)vr * 8;
    float sm[8], ss[8];
    float4 a = p[0];
    float m1 = a.x, m2 = a.y; int k1 = __float_as_int(a.z);
    sm[0] = a.x; ss[0] = a.w;
    #pragma unroll
    for (int j = 1; j < 8; j++) {
        float4 b = p[j];
        sm[j] = b.x; ss[j] = b.w;
        int kk = __float_as_int(b.z);
        if (b.x > m1 || (b.x == m1 && kk < k1)) { m2 = fmaxf(m1, b.y); m1 = b.x; k1 = kk; }
        else m2 = fmaxf(m2, b.x);
    }
    float S = 0.f;
    #pragma unroll
    for (int j = 0; j < 8; j++) S += ss[j] * __expf(sm[j] - m1);
    if (vr < 43008) { idx1[vr] = k1; prob[vr] = 1.0f / S; }
    else idx2[vr - 43008] = k1;
    if (m1 - m2 < EPS_V) { int pos = atomicAdd(cnt, 1); rlist[pos] = vr; }
}

// ---- exact fp64 recompute for flagged rows (idx + prob)
__launch_bounds__(256)
__global__ void rescue_exact(const float* __restrict__ feat,
                             const float* __restrict__ codebooks,
                             const double* __restrict__ cnd,
                             const int* __restrict__ rlist, const int* __restrict__ cnt,
                             int* __restrict__ idx1, int* __restrict__ idx2,
                             float* __restrict__ prob) {
    __shared__ double sfd[256];
    __shared__ double rv[4]; __shared__ int rk[4]; __shared__ double rs[4];
    __shared__ double gvmax; __shared__ int gkmax;
    int tid = threadIdx.x;
    int lane = tid & 63, wave = tid >> 6;
    int n = cnt[0];
    for (int e = blockIdx.x; e < n; e += gridDim.x) {
        int vr = rlist[e];
        int book = vr >= 43008;
        int fr = book ? vr - 43008 : vr;
        sfd[tid] = (double)feat[(size_t)fr * 256 + tid];
        __syncthreads();
        const float* cb = codebooks + (size_t)book * 131072;
        double vloc[2]; int kk[2];
        #pragma unroll
        for (int h = 0; h < 2; h++) {
            int k = h * 256 + tid;
            const float* cp = cb + (size_t)k * 256;
            double dot = 0.0;
            for (int c = 0; c < 256; c++) dot = fma((double)cp[c], sfd[c], dot);
            vloc[h] = 2.0 * dot - cnd[book * 512 + k];
            kk[h] = k;
        }
        double bv = vloc[0]; int bk = kk[0];
        if (vloc[1] > bv || (vloc[1] == bv && kk[1] < bk)) { bv = vloc[1]; bk = kk[1]; }
        #pragma unroll
        for (int off = 32; off; off >>= 1) {
            double vo = __shfl_xor(bv, off);
            int ko = __shfl_xor(bk, off);
            if (vo > bv || (vo == bv && ko < bk)) { bv = vo; bk = ko; }
        }
        if (lane == 0) { rv[wave] = bv; rk[wave] = bk; }
        __syncthreads();
        if (tid == 0) {
            double v0 = rv[0]; int K = rk[0];
            #pragma unroll
            for (int w = 1; w < 4; w++)
                if (rv[w] > v0 || (rv[w] == v0 && rk[w] < K)) { v0 = rv[w]; K = rk[w]; }
            gvmax = v0; gkmax = K;
        }
        __syncthreads();
        double vm = gvmax;
        double s = exp(vloc[0] - vm) + exp(vloc[1] - vm);
        #pragma unroll
        for (int off = 32; off; off >>= 1) s += __shfl_xor(s, off);
        if (lane == 0) rs[wave] = s;
        __syncthreads();
        if (tid == 0) {
            double S = ((rs[0] + rs[1]) + rs[2]) + rs[3];
            if (book) idx2[fr] = gkmax;
            else { idx1[vr] = gkmax; prob[vr] = (float)(1.0 / S); }
        }
        __syncthreads();
    }
}

// ---- fuse stage 1: decide per pixel; defer prob-fragile pixels to fuse2
__launch_bounds__(256)
__global__ void fuse1(const float* __restrict__ feat,
                      const float* __restrict__ prob,
                      const int* __restrict__ idx1, const int* __restrict__ idx2,
                      const float* __restrict__ codebooks,
                      float* __restrict__ out0, float* __restrict__ outZ,
                      float* __restrict__ outS,
                      int* __restrict__ dlist, int* __restrict__ cnt) {
    __shared__ int rsel_s[64], i1_s[64], i2_s[64], defer_s[64];
    int tid = threadIdx.x;
    int b = blockIdx.x >> 6, y = blockIdx.x & 63;

    if (tid < 64) {
        int x = tid;
        int r0 = (b * 64 + y) * 64 + x;
        int r1 = 32768 + (b * 32 + (y >> 1)) * 32 + (x >> 1);
        int r2 = 40960 + (b * 16 + (y >> 2)) * 16 + (x >> 2);
        float p0 = prob[r0], p1 = prob[r1], p2 = prob[r2];
        int rsel = r0; float best = p0;          // strict > keeps first-max
        if (p1 > best) { best = p1; rsel = r1; }
        if (p2 > best) { best = p2; rsel = r2; }
        float second = (rsel == r0) ? fmaxf(p1, p2)
                     : (rsel == r1) ? fmaxf(p0, p2) : fmaxf(p0, p1);
        int defer = (best - second < EPS_P_REL * best) ? 1 : 0;
        defer_s[x] = defer;
        if (defer) {
            int pos = atomicAdd(cnt + 1, 1);
            dlist[pos] = (b << 12) | (y << 6) | x;
            rsel_s[x] = r0; i1_s[x] = 0; i2_s[x] = 0;   // unused
        } else {
            int i1 = idx1[rsel], i2 = idx2[r0];
            rsel_s[x] = rsel; i1_s[x] = i1; i2_s[x] = i2;
            size_t zb = (size_t)b * 8192 + (size_t)y * 64 + x;
            outZ[zb] = (float)i1;
            outZ[zb + 4096] = (float)i2;
        }
    }
    __syncthreads();

    int x = tid & 63, cc = tid >> 6;
    int r0 = (b * 64 + y) * 64 + x;
    const float* e0p = feat + (size_t)r0 * 256;
    const float* e1p = feat + (size_t)rsel_s[x] * 256;
    const float* q1p = codebooks + (size_t)i1_s[x] * 256;
    const float* q2p = codebooks + (size_t)(512 + i2_s[x]) * 256;
    int defer = defer_s[x];
    for (int it = 0; it < 64; it++) {
        int c = it * 4 + cc;
        float e0 = e0p[c];
        size_t o = (((size_t)b * 256 + c) * 64 + y) * 64 + x;
        out0[o] = e0;                              // out0 never depends on decisions
        if (!defer) {
            float e1 = e1p[c], q1 = q1p[c], q2 = q2p[c];
            float ef = (e1 + e0) * 0.5f;
            float qf = (q1 + q2) * 0.5f;
            outS[o] = ef + (qf - ef);
        }
    }
}

// ---- fuse stage 2: deferred pixels, full fp64 (3 rows x 512 codes each)
__launch_bounds__(256)
__global__ void fuse2(const float* __restrict__ feat,
                      const float* __restrict__ codebooks,
                      const double* __restrict__ cnd,
                      const int* __restrict__ idx2,
                      const int* __restrict__ dlist, const int* __restrict__ cnt,
                      float* __restrict__ outZ, float* __restrict__ outS) {
    __shared__ double sfd[256];
    __shared__ double rv[4]; __shared__ int rk[4]; __shared__ double rs[4];
    __shared__ double gvmax;
    __shared__ double pRes[3]; __shared__ int kRes[3];
    __shared__ int selS, i2S;
    int tid = threadIdx.x;
    int lane = tid & 63, wave = tid >> 6;
    int n = cnt[1];
    for (int e = blockIdx.x; e < n; e += gridDim.x) {
        int px = dlist[e];
        int b = px >> 12, y = (px >> 6) & 63, x = px & 63;
        int r0 = (b * 64 + y) * 64 + x;
        int r1 = 32768 + (b * 32 + (y >> 1)) * 32 + (x >> 1);
        int r2 = 40960 + (b * 16 + (y >> 2)) * 16 + (x >> 2);
        int rows[3] = {r0, r1, r2};
        for (int s3 = 0; s3 < 3; s3++) {
            sfd[tid] = (double)feat[(size_t)rows[s3] * 256 + tid];
            __syncthreads();
            double vloc[2];
            #pragma unroll
            for (int h = 0; h < 2; h++) {
                int k = h * 256 + tid;
                const float* cp = codebooks + (size_t)k * 256;
                double dot = 0.0;
                for (int c = 0; c < 256; c++) dot = fma((double)cp[c], sfd[c], dot);
                vloc[h] = 2.0 * dot - cnd[k];
            }
            double bv = vloc[0]; int bk = tid;
            if (vloc[1] > bv) { bv = vloc[1]; bk = tid + 256; }
            #pragma unroll
            for (int off = 32; off; off >>= 1) {
                double vo = __shfl_xor(bv, off);
                int ko = __shfl_xor(bk, off);
                if (vo > bv || (vo == bv && ko < bk)) { bv = vo; bk = ko; }
            }
            if (lane == 0) { rv[wave] = bv; rk[wave] = bk; }
            __syncthreads();
            if (tid == 0) {
                double v0 = rv[0]; int K = rk[0];
                #pragma unroll
                for (int w = 1; w < 4; w++)
                    if (rv[w] > v0 || (rv[w] == v0 && rk[w] < K)) { v0 = rv[w]; K = rk[w]; }
                gvmax = v0; kRes[s3] = K;
            }
            __syncthreads();
            double vm = gvmax;
            double s = exp(vloc[0] - vm) + exp(vloc[1] - vm);
            #pragma unroll
            for (int off = 32; off; off >>= 1) s += __shfl_xor(s, off);
            if (lane == 0) rs[wave] = s;
            __syncthreads();
            if (tid == 0) pRes[s3] = 1.0 / (((rs[0] + rs[1]) + rs[2]) + rs[3]);
            __syncthreads();
        }
        if (tid == 0) {
            int sel = 0; double best = pRes[0];
            if (pRes[1] > best) { best = pRes[1]; sel = 1; }
            if (pRes[2] > best) { best = pRes[2]; sel = 2; }
            selS = sel;
            int i2 = idx2[r0];
            i2S = i2;
            size_t zb = (size_t)b * 8192 + (size_t)y * 64 + x;
            outZ[zb] = (float)kRes[sel];
            outZ[zb + 4096] = (float)i2;
        }
        __syncthreads();
        int sel = selS;
        int c = tid;
        float e0 = feat[(size_t)r0 * 256 + c];
        float e1 = feat[(size_t)rows[sel] * 256 + c];
        float q1 = codebooks[(size_t)kRes[sel] * 256 + c];
        float q2 = codebooks[(size_t)(512 + i2S) * 256 + c];
        float ef = (e1 + e0) * 0.5f;
        float qf = (q1 + q2) * 0.5f;
        size_t o = (((size_t)b * 256 + c) * 64 + y) * 64 + x;
        outS[o] = ef + (qf - ef);
        __syncthreads();
    }
}

extern "C" void kernel_launch(void* const* d_in, const int* in_sizes, int n_in,
                              void* d_out, int out_size, void* d_ws, size_t ws_size,
                              hipStream_t stream) {
    (void)in_sizes; (void)n_in; (void)out_size; (void)ws_size;
    const float* image     = (const float*)d_in[0];   // [8,3,256,256]
    const float* conv_w    = (const float*)d_in[1];   // [256,3,4,4]
    const float* conv_b    = (const float*)d_in[2];   // [256]
    const float* codebooks = (const float*)d_in[3];   // [4,512,256]

    float*  ws    = (float*)d_ws;
    float*  feat  = ws + FEAT_OFF;
    float*  parts = ws + PART_OFF;
    float*  prob  = ws + PROB_OFF;
    int*    idx1  = (int*)(ws + IDX1_OFF);
    int*    idx2  = (int*)(ws + IDX2_OFF);
    float*  cnf   = ws + CNF_OFF;
    double* cnd   = (double*)(ws + CND_OFF);
    unsigned short* cbs = (unsigned short*)(ws + CBS_OFF);
    float*  img1  = ws + IMG1_OFF;
    float*  img2  = ws + IMG2_OFF;
    int*    rlist = (int*)(ws + RLIST_OFF);
    int*    dlist = (int*)(ws + DLIST_OFF);
    int*    cnt   = (int*)(ws + CNT_OFF);

    float* out  = (float*)d_out;
    float* out0 = out;
    float* outZ = out + 8388608;
    float* outS = out + 8454144;
    // d_out doubles as scratch for the bf16 feat planes until fuse1 runs;
    // fuse1/fuse2 rewrite every output byte afterwards.
    unsigned short* featbf = (unsigned short*)d_out;

    zero_cnt<<<1, 64, 0, stream>>>(cnt);
    ds_kernel<<<1536, 256, 0, stream>>>(image, img1, 128, 128, 0, 2);
    ds_kernel<<<384, 256, 0, stream>>>(image, img2, 64, 64, 1, 4);
    cnorm_kernel<<<1024, 64, 0, stream>>>(codebooks, cnd, cnf);
    split_cb<<<1024, 256, 0, stream>>>(codebooks, cbs);
    encode_all<<<896, 256, 0, stream>>>(image, img1, img2, conv_w, conv_b, feat, featbf);
    match_bulk<<<2368, 256, 0, stream>>>(featbf, cbs, cnf, parts);
    combine_rows<<<296, 256, 0, stream>>>(parts, idx1, idx2, prob, rlist, cnt);
    rescue_exact<<<1024, 256, 0, stream>>>(feat, codebooks, cnd, rlist, cnt, idx1, idx2, prob);
    fuse1<<<512, 256, 0, stream>>>(feat, prob, idx1, idx2, codebooks, out0, outZ, outS, dlist, cnt);
    fuse2<<<512, 256, 0, stream>>>(feat, codebooks, cnd, idx2, dlist, cnt, outZ, outS);
}

// Round 2
// 356.036 us; speedup vs baseline: 1.1953x; 1.0696x over previous
//
#include <hip/hip_runtime.h>
#include <math.h>

// ---------------------------------------------------------------------------
// VQVAEZMultiScale round 6 — swapped-operand MFMA epilogue + 2-phase dbuf.
//   Round-5 diagnosis: epilogue lane-axis reduction (~1300 VALU insts/wave)
//   rivaled MFMA work; 4-way LDS bank conflicts on fragment reads; no
//   staging pipeline (stage latency exposed at every barrier).
//   Changes:
//     * match_bulk computes mfma(codes, feat) -> D[code][featrow]: the
//       512-code reduce per row is now 16 in-thread values + 2 shfl steps
//       (over lq) instead of 16x 4-step shfl chains over lm.
//     * book-1 blocks (idx2-only) skip exp/S (prob never consumed).
//     * swizzle upgraded to q ^= (row&3)^((row>>2)&3): 2-way max bank
//       aliasing on ds_read_b128 (was 4-way). Producers updated to match.
//     * double-buffered LDS (64 KB): STAGE(kc+1) issued before compute(kc),
//       one barrier per kc -> global-load latency hidden under MFMA.
// Workspace layout (float units), total ~57.7 MB (unchanged):
//   feat   [43008][256] f32        @ 0
//   partials [75776][8] float4     @ 11010048
//   prob   f32[43008]              @ 13434880
//   idx1   int[43008]              @ 13477888
//   idx2   int[32768]              @ 13520896
//   cnf    f32[1024]               @ 13553664
//   cnd    double[1024]            @ 13554688
//   cbs    bf16 tiled [book][split][codeblk][kc][128][32] @ 13556736
//   img1   [8][3][128][128]        @ 13818880
//   img2   [8][3][64][64]          @ 14212096
//   rlist  int[75776]              @ 14310400
//   dlist  int[32768]              @ 14386176
//   cnt    int[2]                  @ 14418944
// d_out scratch reuse (before fuse1): bf16 feat planes
//   [split][336 rowblk][8 kc][128][32] ushort, 22,020,096 ushorts = 44 MB.
// Output: out0 @0, zidx @8388608 (as float), ste0 @8454144 (all f32, NCHW)
// ---------------------------------------------------------------------------

#define FEAT_OFF   0
#define PART_OFF   11010048
#define PROB_OFF   13434880
#define IDX1_OFF   13477888
#define IDX2_OFF   13520896
#define CNF_OFF    13553664
#define CND_OFF    13554688
#define CBS_OFF    13556736
#define IMG1_OFF   13818880
#define IMG2_OFF   14212096
#define RLIST_OFF  14310400
#define DLIST_OFF  14386176
#define CNT_OFF    14418944

#define PLANE_STRIDE 11010048   // ushorts per split plane (336*8*128*32)

#define EPS_V 1e-3f          // v abs error <= ~3e-5 worst-case -> 30x margin
#define EPS_P_REL 2e-3f      // prob rel error <= ~1e-4 -> 20x margin

typedef __attribute__((ext_vector_type(8))) short short8;
typedef __attribute__((ext_vector_type(4))) float f32x4;

__device__ inline unsigned short f2bf(float x) {
    unsigned u = __float_as_uint(x);
    return (unsigned short)((u + 0x7FFFu + ((u >> 16) & 1u)) >> 16);
}
__device__ inline float bf2f(unsigned short h) {
    return __uint_as_float(((unsigned)h) << 16);
}
// row-dependent channel-quad swizzle: 2-way max bank aliasing on b128 reads
__device__ inline int rswz(int row) { return (row & 3) ^ ((row >> 2) & 3); }

// global -> LDS direct copy, 16 B per lane. LDS dest must be wave-uniform.
__device__ inline void glds16(const unsigned short* g, unsigned short* l) {
    __builtin_amdgcn_global_load_lds(
        (const __attribute__((address_space(1))) void*)g,
        (__attribute__((address_space(3))) void*)l, 16, 0, 0);
}

__global__ void zero_cnt(int* cnt) { if (threadIdx.x < 2) cnt[threadIdx.x] = 0; }

// ---- bilinear downsample (reference order: H-average first, then W)
__global__ void ds_kernel(const float* __restrict__ img, float* __restrict__ out,
                          int Hout, int Wout, int o, int f) {
    int i = blockIdx.x * blockDim.x + threadIdx.x;
    if (i >= 8 * 3 * Hout * Wout) return;
    int x = i % Wout;
    int t = i / Wout;
    int y = t % Hout;
    int bc = t / Hout;
    const float* base = img + ((size_t)bc * 256 + (size_t)(y * f + o)) * 256;
    int cx = x * f + o;
    float v00 = base[cx],     v10 = base[256 + cx];
    float v01 = base[cx + 1], v11 = base[256 + cx + 1];
    out[i] = ((v00 + v10) * 0.5f + (v01 + v11) * 0.5f) * 0.5f;
}

// ---- per-code squared norms, fp64 + f32 copies
__global__ void cnorm_kernel(const float* __restrict__ cb, double* __restrict__ cnd,
                             float* __restrict__ cnf) {
    int row = blockIdx.x;                    // 0..1023
    const float* p = cb + (size_t)row * 256;
    int lane = threadIdx.x;                  // 64
    double s = 0.0;
    for (int c = lane; c < 256; c += 64) {
        double v = (double)p[c];
        s = fma(v, v, s);
    }
    #pragma unroll
    for (int off = 32; off; off >>= 1) s += __shfl_down(s, off);
    if (lane == 0) { cnd[row] = s; cnf[row] = (float)s; }
}

// ---- split both codebooks into bf16 hi/lo planes, tiled+swizzled layout:
//      cbs[book][split][codeblk][kc][row(128)][32] with q ^= rswz(row).
__global__ void split_cb(const float* __restrict__ codebooks, unsigned short* __restrict__ cbs) {
    int i = blockIdx.x * 256 + threadIdx.x;      // over 2*512*256 = 262144
    if (i >= 262144) return;
    int book = i >> 17, rem = i & 131071;        // rem = code*256 + ch
    int code = rem >> 8, ch = rem & 255;
    float c = codebooks[(size_t)book * 131072 + rem];
    unsigned short h0 = f2bf(c);
    unsigned short h1 = f2bf(c - bf2f(h0));
    int codeblk = code >> 7, row = code & 127;
    int kc = ch >> 5, q = (ch >> 3) & 3, j = ch & 7;
    int qs = q ^ rswz(row);
    size_t off = ((((size_t)(book * 2) * 4 + codeblk) * 8 + kc) * 128 + row) * 32 + qs * 8 + j;
    cbs[off] = h0;                               // split 0
    cbs[off + 4 * 32768] = h1;                   // split 1 (stride 4 codeblk tiles)
}

// ---- stride-4 patchify conv, all 3 scales in one launch.
//      Also emits bf16 hi/lo planes of feat in the tiled+swizzled layout.
__launch_bounds__(256)
__global__ void encode_all(const float* __restrict__ image,
                           const float* __restrict__ img1,
                           const float* __restrict__ img2,
                           const float* __restrict__ w,
                           const float* __restrict__ bias,
                           float* __restrict__ feat,
                           unsigned short* __restrict__ featbf) {
    __shared__ float patch[12 * 256];
    int bid = blockIdx.x;
    const float* img; int Hout, rowbase, local;
    if (bid < 512)      { img = image; Hout = 64; rowbase = 0;     local = bid; }
    else if (bid < 768) { img = img1;  Hout = 32; rowbase = 32768; local = bid - 512; }
    else                { img = img2;  Hout = 16; rowbase = 40960; local = bid - 768; }
    int Wout = Hout;
    int tid = threadIdx.x;
    int b = local / Hout, y = local % Hout;
    int Himg = Hout * 4, Wimg = Wout * 4;

    const float* ibase = img + (size_t)b * 3 * Himg * Wimg;
    int nload = 12 * Wimg;
    for (int i = tid; i < nload; i += 256) {
        int col = i % Wimg, r = i / Wimg;    // r = ci*4 + kh
        int ci = r >> 2, kh = r & 3;
        patch[r * Wimg + col] = ibase[((size_t)ci * Himg + 4 * y + kh) * Wimg + col];
    }
    float wr[48];
    #pragma unroll
    for (int j = 0; j < 48; j++) wr[j] = w[tid * 48 + j];
    float bv = bias[tid];
    __syncthreads();

    int kc = tid >> 5, qch = (tid >> 3) & 3, jch = tid & 7;
    int rb = rowbase + (b * Hout + y) * Wout;
    for (int x = 0; x < Wout; x++) {
        float acc = 0.f;
        #pragma unroll
        for (int ci = 0; ci < 3; ci++)
            #pragma unroll
            for (int kh = 0; kh < 4; kh++) {
                const float* pr = &patch[(ci * 4 + kh) * Wimg + 4 * x];
                #pragma unroll
                for (int kw = 0; kw < 4; kw++)
                    acc = fmaf(pr[kw], wr[ci * 16 + kh * 4 + kw], acc);
            }
        float val = acc + bv;
        int r = rb + x;
        feat[(size_t)r * 256 + tid] = val;
        unsigned short hi = f2bf(val);
        unsigned short lo = f2bf(val - bf2f(hi));
        int rowblk = r >> 7, rrow = r & 127;
        int qs = qch ^ rswz(rrow);
        size_t off = (((size_t)rowblk * 8 + kc) * 128 + rrow) * 32 + qs * 8 + jch;
        featbf[off] = hi;
        featbf[off + PLANE_STRIDE] = lo;
    }
}

// ---- bulk MFMA match. Block: 128 virtual-rows x 128 codes; grid 592x4.
//      DMA staging (double-buffered) + swapped-operand MFMA: D[code][featrow]
//      so the per-row 512-code reduce is in-thread (16 vals) + 2 shfl steps.
__launch_bounds__(256, 2)
__global__ void match_bulk(const unsigned short* __restrict__ featbf,
                           const unsigned short* __restrict__ cbs,
                           const float* __restrict__ cnf,
                           float* __restrict__ partials) {
    __shared__ unsigned short A0s[2][4096], A1s[2][4096], B0s[2][4096], B1s[2][4096];
    // bijective XCD swizzle: 2368 = 8*296; co-locate the 4 codeblk blocks of a
    // rowtile on one XCD L2 so the feat tile is fetched once, not 4x.
    int bid0 = blockIdx.x;
    int bid = (bid0 & 7) * 296 + (bid0 >> 3);
    int codeblk = bid & 3, rowtile = bid >> 2;     // 4 x 592
    int book = (rowtile >= 336) ? 1 : 0;
    int rowblk = book ? rowtile - 336 : rowtile;
    int vr0 = rowtile * 128;
    int tid = threadIdx.x;
    int wid = tid >> 6, l = tid & 63;
    int waveY = wid & 1, waveX = wid >> 1;
    int lm = l & 15, lq = l >> 4;
    int slot = lq ^ rswz(lm);                      // lane-constant swizzled quad
    int wlds = wid * 512;                          // ushort units, 1 KiB chunks

    // acc[ct][rt]: row (lq*4+j) = code within ct-tile, col (lm) = feat row
    f32x4 acc[4][4];
    #pragma unroll
    for (int ct = 0; ct < 4; ct++)
        #pragma unroll
        for (int rt = 0; rt < 4; rt++) acc[ct][rt] = (f32x4)0.0f;

    const unsigned short* gA0 = featbf + (size_t)rowblk * 32768 + tid * 8;
    const unsigned short* gA1 = gA0 + PLANE_STRIDE;
    const unsigned short* gB0 = cbs + ((size_t)(book * 8) + codeblk) * 32768 + tid * 8;
    const unsigned short* gB1 = gB0 + 4 * 32768;

    auto STAGE = [&](int buf, int kc) {
        const unsigned short* ga0 = gA0 + kc * 4096;
        const unsigned short* ga1 = gA1 + kc * 4096;
        const unsigned short* gb0 = gB0 + kc * 4096;
        const unsigned short* gb1 = gB1 + kc * 4096;
        #pragma unroll
        for (int i = 0; i < 2; i++) {
            glds16(ga0 + i * 2048, &A0s[buf][i * 2048 + wlds]);
            glds16(ga1 + i * 2048, &A1s[buf][i * 2048 + wlds]);
            glds16(gb0 + i * 2048, &B0s[buf][i * 2048 + wlds]);
            glds16(gb1 + i * 2048, &B1s[buf][i * 2048 + wlds]);
        }
    };

    STAGE(0, 0);
    __syncthreads();

    #pragma unroll
    for (int kc = 0; kc < 8; kc++) {
        int cur = kc & 1;
        if (kc < 7) STAGE(cur ^ 1, kc + 1);        // prefetch next tile
        short8 a0[4], a1[4], b0[4], b1[4];
        #pragma unroll
        for (int t = 0; t < 4; t++) {
            int ra = (waveY * 64 + t * 16 + lm) * 32 + slot * 8;
            int rbx = (waveX * 64 + t * 16 + lm) * 32 + slot * 8;
            a0[t] = *(const short8*)&A0s[cur][ra];
            a1[t] = *(const short8*)&A1s[cur][ra];
            b0[t] = *(const short8*)&B0s[cur][rbx];
            b1[t] = *(const short8*)&B1s[cur][rbx];
        }
        #pragma unroll
        for (int ct = 0; ct < 4; ct++)
            #pragma unroll
            for (int rt = 0; rt < 4; rt++) {
                acc[ct][rt] = __builtin_amdgcn_mfma_f32_16x16x32_bf16(b0[ct], a0[rt], acc[ct][rt], 0, 0, 0);
                acc[ct][rt] = __builtin_amdgcn_mfma_f32_16x16x32_bf16(b1[ct], a0[rt], acc[ct][rt], 0, 0, 0);
                acc[ct][rt] = __builtin_amdgcn_mfma_f32_16x16x32_bf16(b0[ct], a1[rt], acc[ct][rt], 0, 0, 0);
            }
        __syncthreads();                           // drains stage vmcnt too
    }

    // per-thread codes: kbase + ct*16 + j, all 16 in-register
    int kbase = codeblk * 128 + waveX * 64 + lq * 4;
    float4 cnv4[4];
    #pragma unroll
    for (int ct = 0; ct < 4; ct++)
        cnv4[ct] = *(const float4*)&cnf[book * 512 + kbase + ct * 16];
    float4* part4 = (float4*)partials;

    #pragma unroll
    for (int rt = 0; rt < 4; rt++) {
        float v[4][4];
        #pragma unroll
        for (int ct = 0; ct < 4; ct++) {
            v[ct][0] = 2.0f * acc[ct][rt][0] - cnv4[ct].x;
            v[ct][1] = 2.0f * acc[ct][rt][1] - cnv4[ct].y;
            v[ct][2] = 2.0f * acc[ct][rt][2] - cnv4[ct].z;
            v[ct][3] = 2.0f * acc[ct][rt][3] - cnv4[ct].w;
        }
        // in-thread argmax over 16 codes (ascending index: strict > keeps first)
        float m1 = v[0][0], m2 = -3.4e38f;
        int k1 = kbase;
        #pragma unroll
        for (int ct = 0; ct < 4; ct++)
            #pragma unroll
            for (int j = 0; j < 4; j++) {
                if (ct == 0 && j == 0) continue;
                float val = v[ct][j];
                if (val > m1) { m2 = m1; m1 = val; k1 = kbase + ct * 16 + j; }
                else m2 = fmaxf(m2, val);
            }
        // cross-lane over lq (lanes 16 apart): 2 butterfly steps
        #pragma unroll
        for (int off = 16; off < 64; off <<= 1) {
            float mo1 = __shfl_xor(m1, off);
            float mo2 = __shfl_xor(m2, off);
            int ko1 = __shfl_xor(k1, off);
            if (mo1 > m1 || (mo1 == m1 && ko1 < k1)) { m2 = fmaxf(m1, mo2); m1 = mo1; k1 = ko1; }
            else m2 = fmaxf(m2, mo1);
        }
        float s = 0.f;
        if (!book) {                                // prob never consumed for book 1
            #pragma unroll
            for (int ct = 0; ct < 4; ct++)
                #pragma unroll
                for (int j = 0; j < 4; j++) s += __expf(v[ct][j] - m1);
            #pragma unroll
            for (int off = 16; off < 64; off <<= 1) s += __shfl_xor(s, off);
        }
        if (lq == 0) {
            int vr = vr0 + waveY * 64 + rt * 16 + lm;
            float4 st = make_float4(m1, m2, __int_as_float(k1), s);
            part4[(size_t)vr * 8 + codeblk * 2 + waveX] = st;
        }
    }
}

// ---- combine the 8 per-slice partials of each row; write idx/prob; flag rescues
__global__ void combine_rows(const float* __restrict__ partials,
                             int* __restrict__ idx1, int* __restrict__ idx2,
                             float* __restrict__ prob,
                             int* __restrict__ rlist, int* __restrict__ cnt) {
    int vr = blockIdx.x * 256 + threadIdx.x;      // grid 296*256 = 75776 exact
    const float4* p = (const float4*)partials + (size_t)vr * 8;
    float sm[8], ss[8];
    float4 a = p[0];
    float m1 = a.x, m2 = a.y; int k1 = __float_as_int(a.z);
    sm[0] = a.x; ss[0] = a.w;
    #pragma unroll
    for (int j = 1; j < 8; j++) {
        float4 b = p[j];
        sm[j] = b.x; ss[j] = b.w;
        int kk = __float_as_int(b.z);
        if (b.x > m1 || (b.x == m1 && kk < k1)) { m2 = fmaxf(m1, b.y); m1 = b.x; k1 = kk; }
        else m2 = fmaxf(m2, b.x);
    }
    float S = 0.f;
    #pragma unroll
    for (int j = 0; j < 8; j++) S += ss[j] * __expf(sm[j] - m1);
    if (vr < 43008) { idx1[vr] = k1; prob[vr] = 1.0f / S; }
    else idx2[vr - 43008] = k1;
    if (m1 - m2 < EPS_V) { int pos = atomicAdd(cnt, 1); rlist[pos] = vr; }
}

// ---- exact fp64 recompute for flagged rows (idx + prob)
__launch_bounds__(256)
__global__ void rescue_exact(const float* __restrict__ feat,
                             const float* __restrict__ codebooks,
                             const double* __restrict__ cnd,
                             const int* __restrict__ rlist, const int* __restrict__ cnt,
                             int* __restrict__ idx1, int* __restrict__ idx2,
                             float* __restrict__ prob) {
    __shared__ double sfd[256];
    __shared__ double rv[4]; __shared__ int rk[4]; __shared__ double rs[4];
    __shared__ double gvmax; __shared__ int gkmax;
    int tid = threadIdx.x;
    int lane = tid & 63, wave = tid >> 6;
    int n = cnt[0];
    for (int e = blockIdx.x; e < n; e += gridDim.x) {
        int vr = rlist[e];
        int book = vr >= 43008;
        int fr = book ? vr - 43008 : vr;
        sfd[tid] = (double)feat[(size_t)fr * 256 + tid];
        __syncthreads();
        const float* cb = codebooks + (size_t)book * 131072;
        double vloc[2]; int kk[2];
        #pragma unroll
        for (int h = 0; h < 2; h++) {
            int k = h * 256 + tid;
            const float* cp = cb + (size_t)k * 256;
            double dot = 0.0;
            for (int c = 0; c < 256; c++) dot = fma((double)cp[c], sfd[c], dot);
            vloc[h] = 2.0 * dot - cnd[book * 512 + k];
            kk[h] = k;
        }
        double bv = vloc[0]; int bk = kk[0];
        if (vloc[1] > bv || (vloc[1] == bv && kk[1] < bk)) { bv = vloc[1]; bk = kk[1]; }
        #pragma unroll
        for (int off = 32; off; off >>= 1) {
            double vo = __shfl_xor(bv, off);
            int ko = __shfl_xor(bk, off);
            if (vo > bv || (vo == bv && ko < bk)) { bv = vo; bk = ko; }
        }
        if (lane == 0) { rv[wave] = bv; rk[wave] = bk; }
        __syncthreads();
        if (tid == 0) {
            double v0 = rv[0]; int K = rk[0];
            #pragma unroll
            for (int w = 1; w < 4; w++)
                if (rv[w] > v0 || (rv[w] == v0 && rk[w] < K)) { v0 = rv[w]; K = rk[w]; }
            gvmax = v0; gkmax = K;
        }
        __syncthreads();
        double vm = gvmax;
        double s = exp(vloc[0] - vm) + exp(vloc[1] - vm);
        #pragma unroll
        for (int off = 32; off; off >>= 1) s += __shfl_xor(s, off);
        if (lane == 0) rs[wave] = s;
        __syncthreads();
        if (tid == 0) {
            double S = ((rs[0] + rs[1]) + rs[2]) + rs[3];
            if (book) idx2[fr] = gkmax;
            else { idx1[vr] = gkmax; prob[vr] = (float)(1.0 / S); }
        }
        __syncthreads();
    }
}

// ---- fuse stage 1: decide per pixel; defer prob-fragile pixels to fuse2
__launch_bounds__(256)
__global__ void fuse1(const float* __restrict__ feat,
                      const float* __restrict__ prob,
                      const int* __restrict__ idx1, const int* __restrict__ idx2,
                      const float* __restrict__ codebooks,
                      float* __restrict__ out0, float* __restrict__ outZ,
                      float* __restrict__ outS,
                      int* __restrict__ dlist, int* __restrict__ cnt) {
    __shared__ int rsel_s[64], i1_s[64], i2_s[64], defer_s[64];
    int tid = threadIdx.x;
    int b = blockIdx.x >> 6, y = blockIdx.x & 63;

    if (tid < 64) {
        int x = tid;
        int r0 = (b * 64 + y) * 64 + x;
        int r1 = 32768 + (b * 32 + (y >> 1)) * 32 + (x >> 1);
        int r2 = 40960 + (b * 16 + (y >> 2)) * 16 + (x >> 2);
        float p0 = prob[r0], p1 = prob[r1], p2 = prob[r2];
        int rsel = r0; float best = p0;          // strict > keeps first-max
        if (p1 > best) { best = p1; rsel = r1; }
        if (p2 > best) { best = p2; rsel = r2; }
        float second = (rsel == r0) ? fmaxf(p1, p2)
                     : (rsel == r1) ? fmaxf(p0, p2) : fmaxf(p0, p1);
        int defer = (best - second < EPS_P_REL * best) ? 1 : 0;
        defer_s[x] = defer;
        if (defer) {
            int pos = atomicAdd(cnt + 1, 1);
            dlist[pos] = (b << 12) | (y << 6) | x;
            rsel_s[x] = r0; i1_s[x] = 0; i2_s[x] = 0;   // unused
        } else {
            int i1 = idx1[rsel], i2 = idx2[r0];
            rsel_s[x] = rsel; i1_s[x] = i1; i2_s[x] = i2;
            size_t zb = (size_t)b * 8192 + (size_t)y * 64 + x;
            outZ[zb] = (float)i1;
            outZ[zb + 4096] = (float)i2;
        }
    }
    __syncthreads();

    int x = tid & 63, cc = tid >> 6;
    int r0 = (b * 64 + y) * 64 + x;
    const float* e0p = feat + (size_t)r0 * 256;
    const float* e1p = feat + (size_t)rsel_s[x] * 256;
    const float* q1p = codebooks + (size_t)i1_s[x] * 256;
    const float* q2p = codebooks + (size_t)(512 + i2_s[x]) * 256;
    int defer = defer_s[x];
    for (int it = 0; it < 64; it++) {
        int c = it * 4 + cc;
        float e0 = e0p[c];
        size_t o = (((size_t)b * 256 + c) * 64 + y) * 64 + x;
        out0[o] = e0;                              // out0 never depends on decisions
        if (!defer) {
            float e1 = e1p[c], q1 = q1p[c], q2 = q2p[c];
            float ef = (e1 + e0) * 0.5f;
            float qf = (q1 + q2) * 0.5f;
            outS[o] = ef + (qf - ef);
        }
    }
}

// ---- fuse stage 2: deferred pixels, full fp64 (3 rows x 512 codes each)
__launch_bounds__(256)
__global__ void fuse2(const float* __restrict__ feat,
                      const float* __restrict__ codebooks,
                      const double* __restrict__ cnd,
                      const int* __restrict__ idx2,
                      const int* __restrict__ dlist, const int* __restrict__ cnt,
                      float* __restrict__ outZ, float* __restrict__ outS) {
    __shared__ double sfd[256];
    __shared__ double rv[4]; __shared__ int rk[4]; __shared__ double rs[4];
    __shared__ double gvmax;
    __shared__ double pRes[3]; __shared__ int kRes[3];
    __shared__ int selS, i2S;
    int tid = threadIdx.x;
    int lane = tid & 63, wave = tid >> 6;
    int n = cnt[1];
    for (int e = blockIdx.x; e < n; e += gridDim.x) {
        int px = dlist[e];
        int b = px >> 12, y = (px >> 6) & 63, x = px & 63;
        int r0 = (b * 64 + y) * 64 + x;
        int r1 = 32768 + (b * 32 + (y >> 1)) * 32 + (x >> 1);
        int r2 = 40960 + (b * 16 + (y >> 2)) * 16 + (x >> 2);
        int rows[3] = {r0, r1, r2};
        for (int s3 = 0; s3 < 3; s3++) {
            sfd[tid] = (double)feat[(size_t)rows[s3] * 256 + tid];
            __syncthreads();
            double vloc[2];
            #pragma unroll
            for (int h = 0; h < 2; h++) {
                int k = h * 256 + tid;
                const float* cp = codebooks + (size_t)k * 256;
                double dot = 0.0;
                for (int c = 0; c < 256; c++) dot = fma((double)cp[c], sfd[c], dot);
                vloc[h] = 2.0 * dot - cnd[k];
            }
            double bv = vloc[0]; int bk = tid;
            if (vloc[1] > bv) { bv = vloc[1]; bk = tid + 256; }
            #pragma unroll
            for (int off = 32; off; off >>= 1) {
                double vo = __shfl_xor(bv, off);
                int ko = __shfl_xor(bk, off);
                if (vo > bv || (vo == bv && ko < bk)) { bv = vo; bk = ko; }
            }
            if (lane == 0) { rv[wave] = bv; rk[wave] = bk; }
            __syncthreads();
            if (tid == 0) {
                double v0 = rv[0]; int K = rk[0];
                #pragma unroll
                for (int w = 1; w < 4; w++)
                    if (rv[w] > v0 || (rv[w] == v0 && rk[w] < K)) { v0 = rv[w]; K = rk[w]; }
                gvmax = v0; kRes[s3] = K;
            }
            __syncthreads();
            double vm = gvmax;
            double s = exp(vloc[0] - vm) + exp(vloc[1] - vm);
            #pragma unroll
            for (int off = 32; off; off >>= 1) s += __shfl_xor(s, off);
            if (lane == 0) rs[wave] = s;
            __syncthreads();
            if (tid == 0) pRes[s3] = 1.0 / (((rs[0] + rs[1]) + rs[2]) + rs[3]);
            __syncthreads();
        }
        if (tid == 0) {
            int sel = 0; double best = pRes[0];
            if (pRes[1] > best) { best = pRes[1]; sel = 1; }
            if (pRes[2] > best) { best = pRes[2]; sel = 2; }
            selS = sel;
            int i2 = idx2[r0];
            i2S = i2;
            size_t zb = (size_t)b * 8192 + (size_t)y * 64 + x;
            outZ[zb] = (float)kRes[sel];
            outZ[zb + 4096] = (float)i2;
        }
        __syncthreads();
        int sel = selS;
        int c = tid;
        float e0 = feat[(size_t)r0 * 256 + c];
        float e1 = feat[(size_t)rows[sel] * 256 + c];
        float q1 = codebooks[(size_t)kRes[sel] * 256 + c];
        float q2 = codebooks[(size_t)(512 + i2S) * 256 + c];
        float ef = (e1 + e0) * 0.5f;
        float qf = (q1 + q2) * 0.5f;
        size_t o = (((size_t)b * 256 + c) * 64 + y) * 64 + x;
        outS[o] = ef + (qf - ef);
        __syncthreads();
    }
}

extern "C" void kernel_launch(void* const* d_in, const int* in_sizes, int n_in,
                              void* d_out, int out_size, void* d_ws, size_t ws_size,
                              hipStream_t stream) {
    (void)in_sizes; (void)n_in; (void)out_size; (void)ws_size;
    const float* image     = (const float*)d_in[0];   // [8,3,256,256]
    const float* conv_w    = (const float*)d_in[1];   // [256,3,4,4]
    const float* conv_b    = (const float*)d_in[2];   // [256]
    const float* codebooks = (const float*)d_in[3];   // [4,512,256]

    float*  ws    = (float*)d_ws;
    float*  feat  = ws + FEAT_OFF;
    float*  parts = ws + PART_OFF;
    float*  prob  = ws + PROB_OFF;
    int*    idx1  = (int*)(ws + IDX1_OFF);
    int*    idx2  = (int*)(ws + IDX2_OFF);
    float*  cnf   = ws + CNF_OFF;
    double* cnd   = (double*)(ws + CND_OFF);
    unsigned short* cbs = (unsigned short*)(ws + CBS_OFF);
    float*  img1  = ws + IMG1_OFF;
    float*  img2  = ws + IMG2_OFF;
    int*    rlist = (int*)(ws + RLIST_OFF);
    int*    dlist = (int*)(ws + DLIST_OFF);
    int*    cnt   = (int*)(ws + CNT_OFF);

    float* out  = (float*)d_out;
    float* out0 = out;
    float* outZ = out + 8388608;
    float* outS = out + 8454144;
    // d_out doubles as scratch for the bf16 feat planes until fuse1 runs;
    // fuse1/fuse2 rewrite every output byte afterwards.
    unsigned short* featbf = (unsigned short*)d_out;

    zero_cnt<<<1, 64, 0, stream>>>(cnt);
    ds_kernel<<<1536, 256, 0, stream>>>(image, img1, 128, 128, 0, 2);
    ds_kernel<<<384, 256, 0, stream>>>(image, img2, 64, 64, 1, 4);
    cnorm_kernel<<<1024, 64, 0, stream>>>(codebooks, cnd, cnf);
    split_cb<<<1024, 256, 0, stream>>>(codebooks, cbs);
    encode_all<<<896, 256, 0, stream>>>(image, img1, img2, conv_w, conv_b, feat, featbf);
    match_bulk<<<2368, 256, 0, stream>>>(featbf, cbs, cnf, parts);
    combine_rows<<<296, 256, 0, stream>>>(parts, idx1, idx2, prob, rlist, cnt);
    rescue_exact<<<1024, 256, 0, stream>>>(feat, codebooks, cnd, rlist, cnt, idx1, idx2, prob);
    fuse1<<<512, 256, 0, stream>>>(feat, prob, idx1, idx2, codebooks, out0, outZ, outS, dlist, cnt);
    fuse2<<<512, 256, 0, stream>>>(feat, codebooks, cnd, idx2, dlist, cnt, outZ, outS);
}

// Round 3
// 299.805 us; speedup vs baseline: 1.4195x; 1.1876x over previous
//
#include <hip/hip_runtime.h>
#include <math.h>

// ---------------------------------------------------------------------------
// VQVAEZMultiScale round 7 — counted-vmcnt pipeline + coalesced featbf/fuse1.
//   Round-6 diagnosis: match_bulk at the classic 2-phase ceiling (26% Mfma):
//   __syncthreads drains vmcnt(0) every kc, exposing full stage latency.
//   SQ_LDS_BANK_CONFLICT = glds16_count*8 exactly -> DMA-write floor, not
//   read conflicts. ~265us hides in other kernels: encode_all's 22M scattered
//   2B featbf stores and fuse1's scalar uncoalesced loads.
//   Changes:
//     * match_bulk: depth-2 prefetch with raw s_barrier + counted
//       s_waitcnt vmcnt(8) (never 0 in steady state), lgkmcnt(0)+barrier
//       before buffer overwrite, sched_barrier fences, setprio around MFMA.
//     * encode_all: hi/lo staged via 2KB LDS dbuf; 64 threads flush 16B
//       uint4 stores (1 wave-store per position vs 512 scattered 2B stores).
//     * fuse1: float4 loads on all four channel streams.
// Workspace layout (float units), total ~57.7 MB (unchanged):
//   feat   [43008][256] f32        @ 0
//   partials [75776][8] float4     @ 11010048
//   prob   f32[43008]              @ 13434880
//   idx1   int[43008]              @ 13477888
//   idx2   int[32768]              @ 13520896
//   cnf    f32[1024]               @ 13553664
//   cnd    double[1024]            @ 13554688
//   cbs    bf16 tiled [book][split][codeblk][kc][128][32] @ 13556736
//   img1   [8][3][128][128]        @ 13818880
//   img2   [8][3][64][64]          @ 14212096
//   rlist  int[75776]              @ 14310400
//   dlist  int[32768]              @ 14386176
//   cnt    int[2]                  @ 14418944
// d_out scratch reuse (before fuse1): bf16 feat planes
//   [split][336 rowblk][8 kc][128][32] ushort, 22,020,096 ushorts = 44 MB.
// Output: out0 @0, zidx @8388608 (as float), ste0 @8454144 (all f32, NCHW)
// ---------------------------------------------------------------------------

#define FEAT_OFF   0
#define PART_OFF   11010048
#define PROB_OFF   13434880
#define IDX1_OFF   13477888
#define IDX2_OFF   13520896
#define CNF_OFF    13553664
#define CND_OFF    13554688
#define CBS_OFF    13556736
#define IMG1_OFF   13818880
#define IMG2_OFF   14212096
#define RLIST_OFF  14310400
#define DLIST_OFF  14386176
#define CNT_OFF    14418944

#define PLANE_STRIDE 11010048   // ushorts per split plane (336*8*128*32)

#define EPS_V 1e-3f          // v abs error <= ~3e-5 worst-case -> 30x margin
#define EPS_P_REL 2e-3f      // prob rel error <= ~1e-4 -> 20x margin

typedef __attribute__((ext_vector_type(8))) short short8;
typedef __attribute__((ext_vector_type(4))) float f32x4;

__device__ inline unsigned short f2bf(float x) {
    unsigned u = __float_as_uint(x);
    return (unsigned short)((u + 0x7FFFu + ((u >> 16) & 1u)) >> 16);
}
__device__ inline float bf2f(unsigned short h) {
    return __uint_as_float(((unsigned)h) << 16);
}
// row-dependent channel-quad swizzle: 2-way max bank aliasing on b128 reads
__device__ inline int rswz(int row) { return (row & 3) ^ ((row >> 2) & 3); }

// global -> LDS direct copy, 16 B per lane. LDS dest must be wave-uniform.
__device__ inline void glds16(const unsigned short* g, unsigned short* l) {
    __builtin_amdgcn_global_load_lds(
        (const __attribute__((address_space(1))) void*)g,
        (__attribute__((address_space(3))) void*)l, 16, 0, 0);
}

__global__ void zero_cnt(int* cnt) { if (threadIdx.x < 2) cnt[threadIdx.x] = 0; }

// ---- bilinear downsample (reference order: H-average first, then W)
__global__ void ds_kernel(const float* __restrict__ img, float* __restrict__ out,
                          int Hout, int Wout, int o, int f) {
    int i = blockIdx.x * blockDim.x + threadIdx.x;
    if (i >= 8 * 3 * Hout * Wout) return;
    int x = i % Wout;
    int t = i / Wout;
    int y = t % Hout;
    int bc = t / Hout;
    const float* base = img + ((size_t)bc * 256 + (size_t)(y * f + o)) * 256;
    int cx = x * f + o;
    float v00 = base[cx],     v10 = base[256 + cx];
    float v01 = base[cx + 1], v11 = base[256 + cx + 1];
    out[i] = ((v00 + v10) * 0.5f + (v01 + v11) * 0.5f) * 0.5f;
}

// ---- per-code squared norms, fp64 + f32 copies
__global__ void cnorm_kernel(const float* __restrict__ cb, double* __restrict__ cnd,
                             float* __restrict__ cnf) {
    int row = blockIdx.x;                    // 0..1023
    const float* p = cb + (size_t)row * 256;
    int lane = threadIdx.x;                  // 64
    double s = 0.0;
    for (int c = lane; c < 256; c += 64) {
        double v = (double)p[c];
        s = fma(v, v, s);
    }
    #pragma unroll
    for (int off = 32; off; off >>= 1) s += __shfl_down(s, off);
    if (lane == 0) { cnd[row] = s; cnf[row] = (float)s; }
}

// ---- split both codebooks into bf16 hi/lo planes, tiled+swizzled layout:
//      cbs[book][split][codeblk][kc][row(128)][32] with q ^= rswz(row).
__global__ void split_cb(const float* __restrict__ codebooks, unsigned short* __restrict__ cbs) {
    int i = blockIdx.x * 256 + threadIdx.x;      // over 2*512*256 = 262144
    if (i >= 262144) return;
    int book = i >> 17, rem = i & 131071;        // rem = code*256 + ch
    int code = rem >> 8, ch = rem & 255;
    float c = codebooks[(size_t)book * 131072 + rem];
    unsigned short h0 = f2bf(c);
    unsigned short h1 = f2bf(c - bf2f(h0));
    int codeblk = code >> 7, row = code & 127;
    int kc = ch >> 5, q = (ch >> 3) & 3, j = ch & 7;
    int qs = q ^ rswz(row);
    size_t off = ((((size_t)(book * 2) * 4 + codeblk) * 8 + kc) * 128 + row) * 32 + qs * 8 + j;
    cbs[off] = h0;                               // split 0
    cbs[off + 4 * 32768] = h1;                   // split 1 (stride 4 codeblk tiles)
}

// ---- stride-4 patchify conv, all 3 scales in one launch.
//      Emits feat f32 (coalesced) + bf16 hi/lo planes via LDS pack ->
//      one 16B-per-lane wave store per output position (was 512x 2B scatter).
__launch_bounds__(256)
__global__ void encode_all(const float* __restrict__ image,
                           const float* __restrict__ img1,
                           const float* __restrict__ img2,
                           const float* __restrict__ w,
                           const float* __restrict__ bias,
                           float* __restrict__ feat,
                           unsigned short* __restrict__ featbf) {
    __shared__ float patch[12 * 256];
    __shared__ __align__(16) unsigned short pk[2][2][256];  // [buf][plane][ch]
    int bid = blockIdx.x;
    const float* img; int Hout, rowbase, local;
    if (bid < 512)      { img = image; Hout = 64; rowbase = 0;     local = bid; }
    else if (bid < 768) { img = img1;  Hout = 32; rowbase = 32768; local = bid - 512; }
    else                { img = img2;  Hout = 16; rowbase = 40960; local = bid - 768; }
    int Wout = Hout;
    int tid = threadIdx.x;
    int b = local / Hout, y = local % Hout;
    int Himg = Hout * 4, Wimg = Wout * 4;

    const float* ibase = img + (size_t)b * 3 * Himg * Wimg;
    int nload = 12 * Wimg;
    for (int i = tid; i < nload; i += 256) {
        int col = i % Wimg, r = i / Wimg;    // r = ci*4 + kh
        int ci = r >> 2, kh = r & 3;
        patch[r * Wimg + col] = ibase[((size_t)ci * Himg + 4 * y + kh) * Wimg + col];
    }
    float wr[48];
    #pragma unroll
    for (int j = 0; j < 48; j++) wr[j] = w[tid * 48 + j];
    float bv = bias[tid];
    __syncthreads();

    // featbf flusher mapping (tid < 64): plane, kc-tile, quad-group
    int wp = tid >> 5, wkc = (tid >> 2) & 7, wg = tid & 3;
    int rb = rowbase + (b * Hout + y) * Wout;
    for (int x = 0; x < Wout; x++) {
        float acc = 0.f;
        #pragma unroll
        for (int ci = 0; ci < 3; ci++)
            #pragma unroll
            for (int kh = 0; kh < 4; kh++) {
                const float* pr = &patch[(ci * 4 + kh) * Wimg + 4 * x];
                #pragma unroll
                for (int kw = 0; kw < 4; kw++)
                    acc = fmaf(pr[kw], wr[ci * 16 + kh * 4 + kw], acc);
            }
        float val = acc + bv;
        int r = rb + x;
        feat[(size_t)r * 256 + tid] = val;
        unsigned short hi = f2bf(val);
        unsigned short lo = f2bf(val - bf2f(hi));
        int bufx = x & 1;
        pk[bufx][0][tid] = hi;
        pk[bufx][1][tid] = lo;
        __syncthreads();                    // dbuf: no second barrier needed
        if (tid < 64) {
            int rowblk = r >> 7, rrow = r & 127;
            int ch0 = wkc * 32 + ((wg ^ rswz(rrow)) << 3);
            uint4 v = *(const uint4*)&pk[bufx][wp][ch0];
            size_t off = ((((size_t)rowblk * 8 + wkc) * 128 + rrow) * 32 + wg * 8)
                         + (size_t)wp * PLANE_STRIDE;
            *(uint4*)&featbf[off] = v;
        }
    }
}

// ---- bulk MFMA match. Block: 128 virtual-rows x 128 codes; grid 592x4.
//      Depth-2 DMA pipeline with counted vmcnt (never drains to 0 mid-loop):
//        wait vmcnt(8) -> barrier -> ds_read frags -> lgkmcnt(0) -> barrier
//        -> STAGE(kc+2) into just-read buffer -> MFMA (setprio 1).
__launch_bounds__(256, 2)
__global__ void match_bulk(const unsigned short* __restrict__ featbf,
                           const unsigned short* __restrict__ cbs,
                           const float* __restrict__ cnf,
                           float* __restrict__ partials) {
    __shared__ unsigned short A0s[2][4096], A1s[2][4096], B0s[2][4096], B1s[2][4096];
    // bijective XCD swizzle: 2368 = 8*296; co-locate the 4 codeblk blocks of a
    // rowtile on one XCD L2 so the feat tile is fetched once, not 4x.
    int bid0 = blockIdx.x;
    int bid = (bid0 & 7) * 296 + (bid0 >> 3);
    int codeblk = bid & 3, rowtile = bid >> 2;     // 4 x 592
    int book = (rowtile >= 336) ? 1 : 0;
    int rowblk = book ? rowtile - 336 : rowtile;
    int vr0 = rowtile * 128;
    int tid = threadIdx.x;
    int wid = tid >> 6, l = tid & 63;
    int waveY = wid & 1, waveX = wid >> 1;
    int lm = l & 15, lq = l >> 4;
    int slot = lq ^ rswz(lm);                      // lane-constant swizzled quad
    int wlds = wid * 512;                          // ushort units, 1 KiB chunks

    // epilogue constants loaded up-front; any extra outstanding VMEM op only
    // makes the counted vmcnt waits stricter (vmcnt retires in issue order).
    int kbase = codeblk * 128 + waveX * 64 + lq * 4;
    float4 cnv4[4];
    #pragma unroll
    for (int ct = 0; ct < 4; ct++)
        cnv4[ct] = *(const float4*)&cnf[book * 512 + kbase + ct * 16];

    // acc[ct][rt]: row (lq*4+j) = code within ct-tile, col (lm) = feat row
    f32x4 acc[4][4];
    #pragma unroll
    for (int ct = 0; ct < 4; ct++)
        #pragma unroll
        for (int rt = 0; rt < 4; rt++) acc[ct][rt] = (f32x4)0.0f;

    const unsigned short* gA0 = featbf + (size_t)rowblk * 32768 + tid * 8;
    const unsigned short* gA1 = gA0 + PLANE_STRIDE;
    const unsigned short* gB0 = cbs + ((size_t)(book * 8) + codeblk) * 32768 + tid * 8;
    const unsigned short* gB1 = gB0 + 4 * 32768;

    auto STAGE = [&](int buf, int kc) {            // 8 glds16 = 8 vmcnt units
        const unsigned short* ga0 = gA0 + kc * 4096;
        const unsigned short* ga1 = gA1 + kc * 4096;
        const unsigned short* gb0 = gB0 + kc * 4096;
        const unsigned short* gb1 = gB1 + kc * 4096;
        #pragma unroll
        for (int i = 0; i < 2; i++) {
            glds16(ga0 + i * 2048, &A0s[buf][i * 2048 + wlds]);
            glds16(ga1 + i * 2048, &A1s[buf][i * 2048 + wlds]);
            glds16(gb0 + i * 2048, &B0s[buf][i * 2048 + wlds]);
            glds16(gb1 + i * 2048, &B1s[buf][i * 2048 + wlds]);
        }
    };

    short8 a0[4], a1[4], b0[4], b1[4];
    auto LOADFRAG = [&](int cur) {
        #pragma unroll
        for (int t = 0; t < 4; t++) {
            int ra = (waveY * 64 + t * 16 + lm) * 32 + slot * 8;
            int rbx = (waveX * 64 + t * 16 + lm) * 32 + slot * 8;
            a0[t] = *(const short8*)&A0s[cur][ra];
            a1[t] = *(const short8*)&A1s[cur][ra];
            b0[t] = *(const short8*)&B0s[cur][rbx];
            b1[t] = *(const short8*)&B1s[cur][rbx];
        }
    };
    auto DOMFMA = [&]() {
        __builtin_amdgcn_s_setprio(1);
        #pragma unroll
        for (int ct = 0; ct < 4; ct++)
            #pragma unroll
            for (int rt = 0; rt < 4; rt++) {
                acc[ct][rt] = __builtin_amdgcn_mfma_f32_16x16x32_bf16(b0[ct], a0[rt], acc[ct][rt], 0, 0, 0);
                acc[ct][rt] = __builtin_amdgcn_mfma_f32_16x16x32_bf16(b1[ct], a0[rt], acc[ct][rt], 0, 0, 0);
                acc[ct][rt] = __builtin_amdgcn_mfma_f32_16x16x32_bf16(b0[ct], a1[rt], acc[ct][rt], 0, 0, 0);
            }
        __builtin_amdgcn_s_setprio(0);
    };

    STAGE(0, 0);
    STAGE(1, 1);                                   // 16 outstanding

    // steady state: wait vmcnt(8) = tile kc landed (kc+1's 8 still in flight)
#define MB_STEP(KC)                                                        \
    do {                                                                   \
        asm volatile("s_waitcnt vmcnt(8)" ::: "memory");                   \
        __builtin_amdgcn_s_barrier();                                      \
        __builtin_amdgcn_sched_barrier(0);                                 \
        LOADFRAG((KC) & 1);                                                \
        asm volatile("s_waitcnt lgkmcnt(0)" ::: "memory");                 \
        __builtin_amdgcn_sched_barrier(0);                                 \
        __builtin_amdgcn_s_barrier();                                      \
        __builtin_amdgcn_sched_barrier(0);                                 \
        STAGE((KC) & 1, (KC) + 2);                                         \
        DOMFMA();                                                          \
    } while (0)

    MB_STEP(0); MB_STEP(1); MB_STEP(2); MB_STEP(3); MB_STEP(4); MB_STEP(5);

    // kc = 6: tile 7's 8 loads still in flight; no further staging
    asm volatile("s_waitcnt vmcnt(8)" ::: "memory");
    __builtin_amdgcn_s_barrier();
    __builtin_amdgcn_sched_barrier(0);
    LOADFRAG(0);
    DOMFMA();
    // kc = 7: drain
    asm volatile("s_waitcnt vmcnt(0)" ::: "memory");
    __builtin_amdgcn_s_barrier();
    __builtin_amdgcn_sched_barrier(0);
    LOADFRAG(1);
    DOMFMA();
#undef MB_STEP

    float4* part4 = (float4*)partials;
    #pragma unroll
    for (int rt = 0; rt < 4; rt++) {
        float v[4][4];
        #pragma unroll
        for (int ct = 0; ct < 4; ct++) {
            v[ct][0] = 2.0f * acc[ct][rt][0] - cnv4[ct].x;
            v[ct][1] = 2.0f * acc[ct][rt][1] - cnv4[ct].y;
            v[ct][2] = 2.0f * acc[ct][rt][2] - cnv4[ct].z;
            v[ct][3] = 2.0f * acc[ct][rt][3] - cnv4[ct].w;
        }
        // in-thread argmax over 16 codes (ascending index: strict > keeps first)
        float m1 = v[0][0], m2 = -3.4e38f;
        int k1 = kbase;
        #pragma unroll
        for (int ct = 0; ct < 4; ct++)
            #pragma unroll
            for (int j = 0; j < 4; j++) {
                if (ct == 0 && j == 0) continue;
                float val = v[ct][j];
                if (val > m1) { m2 = m1; m1 = val; k1 = kbase + ct * 16 + j; }
                else m2 = fmaxf(m2, val);
            }
        // cross-lane over lq (lanes 16 apart): 2 butterfly steps
        #pragma unroll
        for (int off = 16; off < 64; off <<= 1) {
            float mo1 = __shfl_xor(m1, off);
            float mo2 = __shfl_xor(m2, off);
            int ko1 = __shfl_xor(k1, off);
            if (mo1 > m1 || (mo1 == m1 && ko1 < k1)) { m2 = fmaxf(m1, mo2); m1 = mo1; k1 = ko1; }
            else m2 = fmaxf(m2, mo1);
        }
        float s = 0.f;
        if (!book) {                                // prob never consumed for book 1
            #pragma unroll
            for (int ct = 0; ct < 4; ct++)
                #pragma unroll
                for (int j = 0; j < 4; j++) s += __expf(v[ct][j] - m1);
            #pragma unroll
            for (int off = 16; off < 64; off <<= 1) s += __shfl_xor(s, off);
        }
        if (lq == 0) {
            int vr = vr0 + waveY * 64 + rt * 16 + lm;
            float4 st = make_float4(m1, m2, __int_as_float(k1), s);
            part4[(size_t)vr * 8 + codeblk * 2 + waveX] = st;
        }
    }
}

// ---- combine the 8 per-slice partials of each row; write idx/prob; flag rescues
__global__ void combine_rows(const float* __restrict__ partials,
                             int* __restrict__ idx1, int* __restrict__ idx2,
                             float* __restrict__ prob,
                             int* __restrict__ rlist, int* __restrict__ cnt) {
    int vr = blockIdx.x * 256 + threadIdx.x;      // grid 296*256 = 75776 exact
    const float4* p = (const float4*)partials + (size_t)vr * 8;
    float sm[8], ss[8];
    float4 a = p[0];
    float m1 = a.x, m2 = a.y; int k1 = __float_as_int(a.z);
    sm[0] = a.x; ss[0] = a.w;
    #pragma unroll
    for (int j = 1; j < 8; j++) {
        float4 b = p[j];
        sm[j] = b.x; ss[j] = b.w;
        int kk = __float_as_int(b.z);
        if (b.x > m1 || (b.x == m1 && kk < k1)) { m2 = fmaxf(m1, b.y); m1 = b.x; k1 = kk; }
        else m2 = fmaxf(m2, b.x);
    }
    float S = 0.f;
    #pragma unroll
    for (int j = 0; j < 8; j++) S += ss[j] * __expf(sm[j] - m1);
    if (vr < 43008) { idx1[vr] = k1; prob[vr] = 1.0f / S; }
    else idx2[vr - 43008] = k1;
    if (m1 - m2 < EPS_V) { int pos = atomicAdd(cnt, 1); rlist[pos] = vr; }
}

// ---- exact fp64 recompute for flagged rows (idx + prob)
__launch_bounds__(256)
__global__ void rescue_exact(const float* __restrict__ feat,
                             const float* __restrict__ codebooks,
                             const double* __restrict__ cnd,
                             const int* __restrict__ rlist, const int* __restrict__ cnt,
                             int* __restrict__ idx1, int* __restrict__ idx2,
                             float* __restrict__ prob) {
    __shared__ double sfd[256];
    __shared__ double rv[4]; __shared__ int rk[4]; __shared__ double rs[4];
    __shared__ double gvmax; __shared__ int gkmax;
    int tid = threadIdx.x;
    int lane = tid & 63, wave = tid >> 6;
    int n = cnt[0];
    for (int e = blockIdx.x; e < n; e += gridDim.x) {
        int vr = rlist[e];
        int book = vr >= 43008;
        int fr = book ? vr - 43008 : vr;
        sfd[tid] = (double)feat[(size_t)fr * 256 + tid];
        __syncthreads();
        const float* cb = codebooks + (size_t)book * 131072;
        double vloc[2]; int kk[2];
        #pragma unroll
        for (int h = 0; h < 2; h++) {
            int k = h * 256 + tid;
            const float* cp = cb + (size_t)k * 256;
            double dot = 0.0;
            for (int c = 0; c < 256; c++) dot = fma((double)cp[c], sfd[c], dot);
            vloc[h] = 2.0 * dot - cnd[book * 512 + k];
            kk[h] = k;
        }
        double bv = vloc[0]; int bk = kk[0];
        if (vloc[1] > bv || (vloc[1] == bv && kk[1] < bk)) { bv = vloc[1]; bk = kk[1]; }
        #pragma unroll
        for (int off = 32; off; off >>= 1) {
            double vo = __shfl_xor(bv, off);
            int ko = __shfl_xor(bk, off);
            if (vo > bv || (vo == bv && ko < bk)) { bv = vo; bk = ko; }
        }
        if (lane == 0) { rv[wave] = bv; rk[wave] = bk; }
        __syncthreads();
        if (tid == 0) {
            double v0 = rv[0]; int K = rk[0];
            #pragma unroll
            for (int w = 1; w < 4; w++)
                if (rv[w] > v0 || (rv[w] == v0 && rk[w] < K)) { v0 = rv[w]; K = rk[w]; }
            gvmax = v0; gkmax = K;
        }
        __syncthreads();
        double vm = gvmax;
        double s = exp(vloc[0] - vm) + exp(vloc[1] - vm);
        #pragma unroll
        for (int off = 32; off; off >>= 1) s += __shfl_xor(s, off);
        if (lane == 0) rs[wave] = s;
        __syncthreads();
        if (tid == 0) {
            double S = ((rs[0] + rs[1]) + rs[2]) + rs[3];
            if (book) idx2[fr] = gkmax;
            else { idx1[vr] = gkmax; prob[vr] = (float)(1.0 / S); }
        }
        __syncthreads();
    }
}

// ---- fuse stage 1: decide per pixel; defer prob-fragile pixels to fuse2
__launch_bounds__(256)
__global__ void fuse1(const float* __restrict__ feat,
                      const float* __restrict__ prob,
                      const int* __restrict__ idx1, const int* __restrict__ idx2,
                      const float* __restrict__ codebooks,
                      float* __restrict__ out0, float* __restrict__ outZ,
                      float* __restrict__ outS,
                      int* __restrict__ dlist, int* __restrict__ cnt) {
    __shared__ int rsel_s[64], i1_s[64], i2_s[64], defer_s[64];
    int tid = threadIdx.x;
    int b = blockIdx.x >> 6, y = blockIdx.x & 63;

    if (tid < 64) {
        int x = tid;
        int r0 = (b * 64 + y) * 64 + x;
        int r1 = 32768 + (b * 32 + (y >> 1)) * 32 + (x >> 1);
        int r2 = 40960 + (b * 16 + (y >> 2)) * 16 + (x >> 2);
        float p0 = prob[r0], p1 = prob[r1], p2 = prob[r2];
        int rsel = r0; float best = p0;          // strict > keeps first-max
        if (p1 > best) { best = p1; rsel = r1; }
        if (p2 > best) { best = p2; rsel = r2; }
        float second = (rsel == r0) ? fmaxf(p1, p2)
                     : (rsel == r1) ? fmaxf(p0, p2) : fmaxf(p0, p1);
        int defer = (best - second < EPS_P_REL * best) ? 1 : 0;
        defer_s[x] = defer;
        if (defer) {
            int pos = atomicAdd(cnt + 1, 1);
            dlist[pos] = (b << 12) | (y << 6) | x;
            rsel_s[x] = r0; i1_s[x] = 0; i2_s[x] = 0;   // unused
        } else {
            int i1 = idx1[rsel], i2 = idx2[r0];
            rsel_s[x] = rsel; i1_s[x] = i1; i2_s[x] = i2;
            size_t zb = (size_t)b * 8192 + (size_t)y * 64 + x;
            outZ[zb] = (float)i1;
            outZ[zb + 4096] = (float)i2;
        }
    }
    __syncthreads();

    int x = tid & 63, cc = tid >> 6;
    int r0 = (b * 64 + y) * 64 + x;
    const float* e0p = feat + (size_t)r0 * 256;
    const float* e1p = feat + (size_t)rsel_s[x] * 256;
    const float* q1p = codebooks + (size_t)i1_s[x] * 256;
    const float* q2p = codebooks + (size_t)(512 + i2_s[x]) * 256;
    int defer = defer_s[x];
    for (int it = 0; it < 16; it++) {
        int c = it * 16 + cc * 4;
        float4 e0 = *(const float4*)&e0p[c];
        size_t o = (((size_t)b * 256 + c) * 64 + y) * 64 + x;
        out0[o]         = e0.x;                    // out0 never depends on decisions
        out0[o + 4096]  = e0.y;
        out0[o + 8192]  = e0.z;
        out0[o + 12288] = e0.w;
        if (!defer) {
            float4 e1 = *(const float4*)&e1p[c];
            float4 q1 = *(const float4*)&q1p[c];
            float4 q2 = *(const float4*)&q2p[c];
            float ef, qf;
            ef = (e1.x + e0.x) * 0.5f; qf = (q1.x + q2.x) * 0.5f; outS[o]         = ef + (qf - ef);
            ef = (e1.y + e0.y) * 0.5f; qf = (q1.y + q2.y) * 0.5f; outS[o + 4096]  = ef + (qf - ef);
            ef = (e1.z + e0.z) * 0.5f; qf = (q1.z + q2.z) * 0.5f; outS[o + 8192]  = ef + (qf - ef);
            ef = (e1.w + e0.w) * 0.5f; qf = (q1.w + q2.w) * 0.5f; outS[o + 12288] = ef + (qf - ef);
        }
    }
}

// ---- fuse stage 2: deferred pixels, full fp64 (3 rows x 512 codes each)
__launch_bounds__(256)
__global__ void fuse2(const float* __restrict__ feat,
                      const float* __restrict__ codebooks,
                      const double* __restrict__ cnd,
                      const int* __restrict__ idx2,
                      const int* __restrict__ dlist, const int* __restrict__ cnt,
                      float* __restrict__ outZ, float* __restrict__ outS) {
    __shared__ double sfd[256];
    __shared__ double rv[4]; __shared__ int rk[4]; __shared__ double rs[4];
    __shared__ double gvmax;
    __shared__ double pRes[3]; __shared__ int kRes[3];
    __shared__ int selS, i2S;
    int tid = threadIdx.x;
    int lane = tid & 63, wave = tid >> 6;
    int n = cnt[1];
    for (int e = blockIdx.x; e < n; e += gridDim.x) {
        int px = dlist[e];
        int b = px >> 12, y = (px >> 6) & 63, x = px & 63;
        int r0 = (b * 64 + y) * 64 + x;
        int r1 = 32768 + (b * 32 + (y >> 1)) * 32 + (x >> 1);
        int r2 = 40960 + (b * 16 + (y >> 2)) * 16 + (x >> 2);
        int rows[3] = {r0, r1, r2};
        for (int s3 = 0; s3 < 3; s3++) {
            sfd[tid] = (double)feat[(size_t)rows[s3] * 256 + tid];
            __syncthreads();
            double vloc[2];
            #pragma unroll
            for (int h = 0; h < 2; h++) {
                int k = h * 256 + tid;
                const float* cp = codebooks + (size_t)k * 256;
                double dot = 0.0;
                for (int c = 0; c < 256; c++) dot = fma((double)cp[c], sfd[c], dot);
                vloc[h] = 2.0 * dot - cnd[k];
            }
            double bv = vloc[0]; int bk = tid;
            if (vloc[1] > bv) { bv = vloc[1]; bk = tid + 256; }
            #pragma unroll
            for (int off = 32; off; off >>= 1) {
                double vo = __shfl_xor(bv, off);
                int ko = __shfl_xor(bk, off);
                if (vo > bv || (vo == bv && ko < bk)) { bv = vo; bk = ko; }
            }
            if (lane == 0) { rv[wave] = bv; rk[wave] = bk; }
            __syncthreads();
            if (tid == 0) {
                double v0 = rv[0]; int K = rk[0];
                #pragma unroll
                for (int w = 1; w < 4; w++)
                    if (rv[w] > v0 || (rv[w] == v0 && rk[w] < K)) { v0 = rv[w]; K = rk[w]; }
                gvmax = v0; kRes[s3] = K;
            }
            __syncthreads();
            double vm = gvmax;
            double s = exp(vloc[0] - vm) + exp(vloc[1] - vm);
            #pragma unroll
            for (int off = 32; off; off >>= 1) s += __shfl_xor(s, off);
            if (lane == 0) rs[wave] = s;
            __syncthreads();
            if (tid == 0) pRes[s3] = 1.0 / (((rs[0] + rs[1]) + rs[2]) + rs[3]);
            __syncthreads();
        }
        if (tid == 0) {
            int sel = 0; double best = pRes[0];
            if (pRes[1] > best) { best = pRes[1]; sel = 1; }
            if (pRes[2] > best) { best = pRes[2]; sel = 2; }
            selS = sel;
            int i2 = idx2[r0];
            i2S = i2;
            size_t zb = (size_t)b * 8192 + (size_t)y * 64 + x;
            outZ[zb] = (float)kRes[sel];
            outZ[zb + 4096] = (float)i2;
        }
        __syncthreads();
        int sel = selS;
        int c = tid;
        float e0 = feat[(size_t)r0 * 256 + c];
        float e1 = feat[(size_t)rows[sel] * 256 + c];
        float q1 = codebooks[(size_t)kRes[sel] * 256 + c];
        float q2 = codebooks[(size_t)(512 + i2S) * 256 + c];
        float ef = (e1 + e0) * 0.5f;
        float qf = (q1 + q2) * 0.5f;
        size_t o = (((size_t)b * 256 + c) * 64 + y) * 64 + x;
        outS[o] = ef + (qf - ef);
        __syncthreads();
    }
}

extern "C" void kernel_launch(void* const* d_in, const int* in_sizes, int n_in,
                              void* d_out, int out_size, void* d_ws, size_t ws_size,
                              hipStream_t stream) {
    (void)in_sizes; (void)n_in; (void)out_size; (void)ws_size;
    const float* image     = (const float*)d_in[0];   // [8,3,256,256]
    const float* conv_w    = (const float*)d_in[1];   // [256,3,4,4]
    const float* conv_b    = (const float*)d_in[2];   // [256]
    const float* codebooks = (const float*)d_in[3];   // [4,512,256]

    float*  ws    = (float*)d_ws;
    float*  feat  = ws + FEAT_OFF;
    float*  parts = ws + PART_OFF;
    float*  prob  = ws + PROB_OFF;
    int*    idx1  = (int*)(ws + IDX1_OFF);
    int*    idx2  = (int*)(ws + IDX2_OFF);
    float*  cnf   = ws + CNF_OFF;
    double* cnd   = (double*)(ws + CND_OFF);
    unsigned short* cbs = (unsigned short*)(ws + CBS_OFF);
    float*  img1  = ws + IMG1_OFF;
    float*  img2  = ws + IMG2_OFF;
    int*    rlist = (int*)(ws + RLIST_OFF);
    int*    dlist = (int*)(ws + DLIST_OFF);
    int*    cnt   = (int*)(ws + CNT_OFF);

    float* out  = (float*)d_out;
    float* out0 = out;
    float* outZ = out + 8388608;
    float* outS = out + 8454144;
    // d_out doubles as scratch for the bf16 feat planes until fuse1 runs;
    // fuse1/fuse2 rewrite every output byte afterwards.
    unsigned short* featbf = (unsigned short*)d_out;

    zero_cnt<<<1, 64, 0, stream>>>(cnt);
    ds_kernel<<<1536, 256, 0, stream>>>(image, img1, 128, 128, 0, 2);
    ds_kernel<<<384, 256, 0, stream>>>(image, img2, 64, 64, 1, 4);
    cnorm_kernel<<<1024, 64, 0, stream>>>(codebooks, cnd, cnf);
    split_cb<<<1024, 256, 0, stream>>>(codebooks, cbs);
    encode_all<<<896, 256, 0, stream>>>(image, img1, img2, conv_w, conv_b, feat, featbf);
    match_bulk<<<2368, 256, 0, stream>>>(featbf, cbs, cnf, parts);
    combine_rows<<<296, 256, 0, stream>>>(parts, idx1, idx2, prob, rlist, cnt);
    rescue_exact<<<1024, 256, 0, stream>>>(feat, codebooks, cnd, rlist, cnt, idx1, idx2, prob);
    fuse1<<<512, 256, 0, stream>>>(feat, prob, idx1, idx2, codebooks, out0, outZ, outS, dlist, cnt);
    fuse2<<<512, 256, 0, stream>>>(feat, codebooks, cnd, idx2, dlist, cnt, outZ, outS);
}

// Round 5
// 283.767 us; speedup vs baseline: 1.4997x; 1.0565x over previous
//
#include <hip/hip_runtime.h>
#include <math.h>

// ---------------------------------------------------------------------------
// VQVAEZMultiScale round 9 — round-8 structure with the B1LOAD asm fixed.
//   Round-8 crash: global_load_dwordx4 inline asm lacked early-clobber on
//   outputs -> LLVM could alias an output quad with the 64-bit address pair
//   (async VMEM writes back AFTER the asm "completes") -> corrupted address
//   on loads 1-3 -> device fault. Fix: "=&v" on all outputs.
//   Structure (from round 8):
//     * match_bulk: B1 operand register-staged via inline-asm
//       global_load_dwordx4 (4 ops/kc/wave, counted in vmcnt with the 6
//       glds16); LDS 64->48 KB -> 3 blocks/CU; launch_bounds(256,3).
//       2 rotating B1 reg sets, loaded AFTER the MFMA that consumed them.
//     * prep kernel fuses zero_cnt + ds x2 + cnorm + split_cb.
//     * encode_all: featbf flush every 4 positions, all 256 threads.
//     * rescue_exact/fuse2: fp64 dot 4-way unrolled + float4 cb loads.
// Workspace layout (float units), total ~57.7 MB (unchanged):
//   feat   [43008][256] f32        @ 0
//   partials [75776][8] float4     @ 11010048
//   prob   f32[43008]              @ 13434880
//   idx1   int[43008]              @ 13477888
//   idx2   int[32768]              @ 13520896
//   cnf    f32[1024]               @ 13553664
//   cnd    double[1024]            @ 13554688
//   cbs    bf16 tiled [book][split][codeblk][kc][128][32] @ 13556736
//   img1   [8][3][128][128]        @ 13818880
//   img2   [8][3][64][64]          @ 14212096
//   rlist  int[75776]              @ 14310400
//   dlist  int[32768]              @ 14386176
//   cnt    int[2]                  @ 14418944
// d_out scratch reuse (before fuse1): bf16 feat planes
//   [split][336 rowblk][8 kc][128][32] ushort, 22,020,096 ushorts = 44 MB.
// Output: out0 @0, zidx @8388608 (as float), ste0 @8454144 (all f32, NCHW)
// ---------------------------------------------------------------------------

#define FEAT_OFF   0
#define PART_OFF   11010048
#define PROB_OFF   13434880
#define IDX1_OFF   13477888
#define IDX2_OFF   13520896
#define CNF_OFF    13553664
#define CND_OFF    13554688
#define CBS_OFF    13556736
#define IMG1_OFF   13818880
#define IMG2_OFF   14212096
#define RLIST_OFF  14310400
#define DLIST_OFF  14386176
#define CNT_OFF    14418944

#define PLANE_STRIDE 11010048   // ushorts per split plane (336*8*128*32)

#define EPS_V 1e-3f          // v abs error <= ~3e-5 worst-case -> 30x margin
#define EPS_P_REL 2e-3f      // prob rel error <= ~1e-4 -> 20x margin

typedef __attribute__((ext_vector_type(8))) short short8;
typedef __attribute__((ext_vector_type(4))) float f32x4;
typedef __attribute__((ext_vector_type(4))) unsigned int u32x4;

__device__ inline unsigned short f2bf(float x) {
    unsigned u = __float_as_uint(x);
    return (unsigned short)((u + 0x7FFFu + ((u >> 16) & 1u)) >> 16);
}
__device__ inline float bf2f(unsigned short h) {
    return __uint_as_float(((unsigned)h) << 16);
}
// row-dependent channel-quad swizzle: 2-way max bank aliasing on b128 reads
__device__ inline int rswz(int row) { return (row & 3) ^ ((row >> 2) & 3); }

// global -> LDS direct copy, 16 B per lane. LDS dest must be wave-uniform.
__device__ inline void glds16(const unsigned short* g, unsigned short* l) {
    __builtin_amdgcn_global_load_lds(
        (const __attribute__((address_space(1))) void*)g,
        (__attribute__((address_space(3))) void*)l, 16, 0, 0);
}

// ---- fused prep: zero_cnt + bilinear ds (2 scales) + code norms + cb split
__launch_bounds__(256)
__global__ void prep(const float* __restrict__ image,
                     const float* __restrict__ codebooks,
                     float* __restrict__ img1, float* __restrict__ img2,
                     double* __restrict__ cnd, float* __restrict__ cnf,
                     unsigned short* __restrict__ cbs, int* __restrict__ cnt) {
    int bid = blockIdx.x, tid = threadIdx.x;
    if (bid == 0 && tid < 2) cnt[tid] = 0;
    if (bid < 1536) {                       // ds scale 1: 128x128, o=0, f=2
        int i = bid * 256 + tid;            // 8*3*128*128 = 393216 exact
        int x = i & 127;
        int t = i >> 7;
        int y = t & 127;
        int bc = t >> 7;
        const float* base = image + ((size_t)bc * 256 + (size_t)(y * 2)) * 256;
        int cx = x * 2;
        float v00 = base[cx],     v10 = base[256 + cx];
        float v01 = base[cx + 1], v11 = base[256 + cx + 1];
        img1[i] = ((v00 + v10) * 0.5f + (v01 + v11) * 0.5f) * 0.5f;
    } else if (bid < 1920) {                // ds scale 2: 64x64, o=1, f=4
        int i = (bid - 1536) * 256 + tid;   // 8*3*64*64 = 98304 exact
        int x = i & 63;
        int t = i >> 6;
        int y = t & 63;
        int bc = t >> 6;
        const float* base = image + ((size_t)bc * 256 + (size_t)(y * 4 + 1)) * 256;
        int cx = x * 4 + 1;
        float v00 = base[cx],     v10 = base[256 + cx];
        float v01 = base[cx + 1], v11 = base[256 + cx + 1];
        img2[i] = ((v00 + v10) * 0.5f + (v01 + v11) * 0.5f) * 0.5f;
    } else if (bid < 2176) {                // code norms: 4 rows/block, 1 wave/row
        int row = (bid - 1920) * 4 + (tid >> 6);
        int lane = tid & 63;
        const float* p = codebooks + (size_t)row * 256;
        double s = 0.0;
        for (int c = lane; c < 256; c += 64) {
            double v = (double)p[c];
            s = fma(v, v, s);
        }
        #pragma unroll
        for (int off = 32; off; off >>= 1) s += __shfl_down(s, off);
        if (lane == 0) { cnd[row] = s; cnf[row] = (float)s; }
    } else {                                // split_cb: tiled+swizzled bf16 planes
        int i = (bid - 2176) * 256 + tid;   // 2*512*256 = 262144 exact
        int book = i >> 17, rem = i & 131071;
        int code = rem >> 8, ch = rem & 255;
        float c = codebooks[(size_t)book * 131072 + rem];
        unsigned short h0 = f2bf(c);
        unsigned short h1 = f2bf(c - bf2f(h0));
        int codeblk = code >> 7, row = code & 127;
        int kc = ch >> 5, q = (ch >> 3) & 3, j = ch & 7;
        int qs = q ^ rswz(row);
        size_t off = ((((size_t)(book * 2) * 4 + codeblk) * 8 + kc) * 128 + row) * 32 + qs * 8 + j;
        cbs[off] = h0;                      // split 0
        cbs[off + 4 * 32768] = h1;          // split 1
    }
}

// ---- stride-4 patchify conv, all 3 scales in one launch.
//      featbf flushed every 4 positions by all 256 threads (uint4 stores).
__launch_bounds__(256)
__global__ void encode_all(const float* __restrict__ image,
                           const float* __restrict__ img1,
                           const float* __restrict__ img2,
                           const float* __restrict__ w,
                           const float* __restrict__ bias,
                           float* __restrict__ feat,
                           unsigned short* __restrict__ featbf) {
    __shared__ float patch[12 * 256];
    __shared__ __align__(16) unsigned short pk[2][4][2][256];  // [buf][pos][plane][ch]
    int bid = blockIdx.x;
    const float* img; int Hout, rowbase, local;
    if (bid < 512)      { img = image; Hout = 64; rowbase = 0;     local = bid; }
    else if (bid < 768) { img = img1;  Hout = 32; rowbase = 32768; local = bid - 512; }
    else                { img = img2;  Hout = 16; rowbase = 40960; local = bid - 768; }
    int Wout = Hout;
    int tid = threadIdx.x;
    int b = local / Hout, y = local % Hout;
    int Himg = Hout * 4, Wimg = Wout * 4;

    const float* ibase = img + (size_t)b * 3 * Himg * Wimg;
    int nload = 12 * Wimg;
    for (int i = tid; i < nload; i += 256) {
        int col = i % Wimg, r = i / Wimg;    // r = ci*4 + kh
        int ci = r >> 2, kh = r & 3;
        patch[r * Wimg + col] = ibase[((size_t)ci * Himg + 4 * y + kh) * Wimg + col];
    }
    float wr[48];
    #pragma unroll
    for (int j = 0; j < 48; j++) wr[j] = w[tid * 48 + j];
    float bv = bias[tid];
    __syncthreads();

    // flush mapping: 256 threads = 4 pos x 2 planes x 8 kc x 4 quad-groups
    int fp = tid >> 6, fwp = (tid >> 5) & 1, fkc = (tid >> 2) & 7, fwg = tid & 3;
    int rb = rowbase + (b * Hout + y) * Wout;
    for (int x0 = 0; x0 < Wout; x0 += 4) {
        int buf = (x0 >> 2) & 1;
        #pragma unroll
        for (int p = 0; p < 4; p++) {
            int x = x0 + p;
            float acc = 0.f;
            #pragma unroll
            for (int ci = 0; ci < 3; ci++)
                #pragma unroll
                for (int kh = 0; kh < 4; kh++) {
                    const float* pr = &patch[(ci * 4 + kh) * Wimg + 4 * x];
                    #pragma unroll
                    for (int kw = 0; kw < 4; kw++)
                        acc = fmaf(pr[kw], wr[ci * 16 + kh * 4 + kw], acc);
                }
            float val = acc + bv;
            feat[(size_t)(rb + x) * 256 + tid] = val;
            unsigned short hi = f2bf(val);
            pk[buf][p][0][tid] = hi;
            pk[buf][p][1][tid] = f2bf(val - bf2f(hi));
        }
        __syncthreads();                   // dbuf: one barrier per 4 positions
        {
            int r = rb + x0 + fp;
            int rowblk = r >> 7, rrow = r & 127;
            int ch0 = fkc * 32 + ((fwg ^ rswz(rrow)) << 3);
            uint4 v = *(const uint4*)&pk[buf][fp][fwp][ch0];
            size_t off = (((size_t)rowblk * 8 + fkc) * 128 + rrow) * 32 + fwg * 8
                       + (size_t)fwp * PLANE_STRIDE;
            *(uint4*)&featbf[off] = v;
        }
    }
}

// ---- bulk MFMA match. Block: 128 virtual-rows x 128 codes; grid 592x4.
//      A0/A1/B0 via glds16 double-buffer (48 KB LDS -> 3 blocks/CU);
//      B1 register-staged via inline-asm global_load_dwordx4 (L2-hot).
//      Counted vmcnt: 10 vmem ops per kc-tile, steady wait vmcnt(10).
__launch_bounds__(256, 3)
__global__ void match_bulk(const unsigned short* __restrict__ featbf,
                           const unsigned short* __restrict__ cbs,
                           const float* __restrict__ cnf,
                           float* __restrict__ partials) {
    __shared__ unsigned short A0s[2][4096], A1s[2][4096], B0s[2][4096];
    // bijective XCD swizzle: 2368 = 8*296; co-locate the 4 codeblk blocks of a
    // rowtile on one XCD L2 so the feat tile is fetched once, not 4x.
    int bid0 = blockIdx.x;
    int bid = (bid0 & 7) * 296 + (bid0 >> 3);
    int codeblk = bid & 3, rowtile = bid >> 2;     // 4 x 592
    int book = (rowtile >= 336) ? 1 : 0;
    int rowblk = book ? rowtile - 336 : rowtile;
    int vr0 = rowtile * 128;
    int tid = threadIdx.x;
    int wid = tid >> 6, l = tid & 63;
    int waveY = wid & 1, waveX = wid >> 1;
    int lm = l & 15, lq = l >> 4;
    int slot = lq ^ rswz(lm);                      // lane-constant swizzled quad
    int wlds = wid * 512;                          // ushort units, 1 KiB chunks

    // acc[ct][rt]: row (lq*4+j) = code within ct-tile, col (lm) = feat row
    f32x4 acc[4][4];
    #pragma unroll
    for (int ct = 0; ct < 4; ct++)
        #pragma unroll
        for (int rt = 0; rt < 4; rt++) acc[ct][rt] = (f32x4)0.0f;

    const unsigned short* gA0 = featbf + (size_t)rowblk * 32768 + tid * 8;
    const unsigned short* gA1 = gA0 + PLANE_STRIDE;
    const unsigned short* gB0 = cbs + ((size_t)(book * 8) + codeblk) * 32768 + tid * 8;
    // per-lane B1 fragment base (matches old LDS-path layout exactly)
    const unsigned short* gB1f = cbs + ((size_t)(book * 8) + codeblk) * 32768 + 131072
                               + ((waveX * 64 + lm) * 32 + slot * 8);

    auto STAGE6 = [&](int buf, int kc) {           // 6 glds16 = 6 vmcnt units
        const unsigned short* ga0 = gA0 + kc * 4096;
        const unsigned short* ga1 = gA1 + kc * 4096;
        const unsigned short* gb0 = gB0 + kc * 4096;
        #pragma unroll
        for (int i = 0; i < 2; i++) {
            glds16(ga0 + i * 2048, &A0s[buf][i * 2048 + wlds]);
            glds16(ga1 + i * 2048, &A1s[buf][i * 2048 + wlds]);
            glds16(gb0 + i * 2048, &B0s[buf][i * 2048 + wlds]);
        }
    };

    u32x4 qA[4], qB[4];                            // 2 rotating B1 reg sets
    auto B1LOAD = [&](u32x4 (&q)[4], int kc) {     // 4 vmcnt units
        const unsigned short* p = gB1f + (size_t)kc * 4096;
        // "=&v" early-clobber: async VMEM dest must NOT alias the 64-bit
        // address pair (round-8 fault) nor each other.
        asm volatile(
            "global_load_dwordx4 %0, %4, off\n\t"
            "global_load_dwordx4 %1, %4, off offset:1024\n\t"
            "global_load_dwordx4 %2, %4, off offset:2048\n\t"
            "global_load_dwordx4 %3, %4, off offset:3072"
            : "=&v"(q[0]), "=&v"(q[1]), "=&v"(q[2]), "=&v"(q[3])
            : "v"(p)
            : "memory");
    };

    short8 a0[4], a1[4], b0[4];
    auto LOADFRAG = [&](int cur) {                 // 12 ds_read_b128
        #pragma unroll
        for (int t = 0; t < 4; t++) {
            int ra = (waveY * 64 + t * 16 + lm) * 32 + slot * 8;
            int rbx = (waveX * 64 + t * 16 + lm) * 32 + slot * 8;
            a0[t] = *(const short8*)&A0s[cur][ra];
            a1[t] = *(const short8*)&A1s[cur][ra];
            b0[t] = *(const short8*)&B0s[cur][rbx];
        }
    };
    auto DOMFMA = [&](u32x4 (&q)[4]) {
        __builtin_amdgcn_s_setprio(1);
        #pragma unroll
        for (int ct = 0; ct < 4; ct++) {
            short8 b1v;
            __builtin_memcpy(&b1v, &q[ct], 16);
            #pragma unroll
            for (int rt = 0; rt < 4; rt++) {
                acc[ct][rt] = __builtin_amdgcn_mfma_f32_16x16x32_bf16(b0[ct], a0[rt], acc[ct][rt], 0, 0, 0);
                acc[ct][rt] = __builtin_amdgcn_mfma_f32_16x16x32_bf16(b1v,    a0[rt], acc[ct][rt], 0, 0, 0);
                acc[ct][rt] = __builtin_amdgcn_mfma_f32_16x16x32_bf16(b0[ct], a1[rt], acc[ct][rt], 0, 0, 0);
            }
        }
        __builtin_amdgcn_s_setprio(0);
    };

    // prologue: tiles 0 and 1 fully issued (tile-ordered: 6g+4b, 6g+4b)
    STAGE6(0, 0); B1LOAD(qA, 0);
    STAGE6(1, 1); B1LOAD(qB, 1);

    // steady state: wait vmcnt(10) = tile kc landed (tile kc+1 still in flight)
#define MB_STEP(KC, QQ)                                                    \
    do {                                                                   \
        asm volatile("s_waitcnt vmcnt(10)" ::: "memory");                  \
        __builtin_amdgcn_s_barrier();                                      \
        __builtin_amdgcn_sched_barrier(0);                                 \
        LOADFRAG((KC) & 1);                                                \
        asm volatile("s_waitcnt lgkmcnt(0)" ::: "memory");                 \
        __builtin_amdgcn_sched_barrier(0);                                 \
        __builtin_amdgcn_s_barrier();                                      \
        __builtin_amdgcn_sched_barrier(0);                                 \
        STAGE6((KC) & 1, (KC) + 2);                                        \
        DOMFMA(QQ);                                                        \
        B1LOAD(QQ, (KC) + 2);                                              \
    } while (0)

    MB_STEP(0, qA); MB_STEP(1, qB); MB_STEP(2, qA);
    MB_STEP(3, qB); MB_STEP(4, qA); MB_STEP(5, qB);
#undef MB_STEP

    // kc = 6: tile 7's 10 ops still in flight; no further staging
    asm volatile("s_waitcnt vmcnt(10)" ::: "memory");
    __builtin_amdgcn_s_barrier();
    __builtin_amdgcn_sched_barrier(0);
    LOADFRAG(0);
    asm volatile("s_waitcnt lgkmcnt(0)" ::: "memory");
    __builtin_amdgcn_sched_barrier(0);
    DOMFMA(qA);
    // kc = 7: drain
    asm volatile("s_waitcnt vmcnt(0)" ::: "memory");
    __builtin_amdgcn_s_barrier();
    __builtin_amdgcn_sched_barrier(0);
    LOADFRAG(1);
    asm volatile("s_waitcnt lgkmcnt(0)" ::: "memory");
    __builtin_amdgcn_sched_barrier(0);
    DOMFMA(qB);

    // per-thread codes: kbase + ct*16 + j, all 16 in-register
    int kbase = codeblk * 128 + waveX * 64 + lq * 4;
    float4 cnv4[4];
    #pragma unroll
    for (int ct = 0; ct < 4; ct++)
        cnv4[ct] = *(const float4*)&cnf[book * 512 + kbase + ct * 16];
    float4* part4 = (float4*)partials;

    #pragma unroll
    for (int rt = 0; rt < 4; rt++) {
        float v[4][4];
        #pragma unroll
        for (int ct = 0; ct < 4; ct++) {
            v[ct][0] = 2.0f * acc[ct][rt][0] - cnv4[ct].x;
            v[ct][1] = 2.0f * acc[ct][rt][1] - cnv4[ct].y;
            v[ct][2] = 2.0f * acc[ct][rt][2] - cnv4[ct].z;
            v[ct][3] = 2.0f * acc[ct][rt][3] - cnv4[ct].w;
        }
        // in-thread argmax over 16 codes (ascending index: strict > keeps first)
        float m1 = v[0][0], m2 = -3.4e38f;
        int k1 = kbase;
        #pragma unroll
        for (int ct = 0; ct < 4; ct++)
            #pragma unroll
            for (int j = 0; j < 4; j++) {
                if (ct == 0 && j == 0) continue;
                float val = v[ct][j];
                if (val > m1) { m2 = m1; m1 = val; k1 = kbase + ct * 16 + j; }
                else m2 = fmaxf(m2, val);
            }
        // cross-lane over lq (lanes 16 apart): 2 butterfly steps
        #pragma unroll
        for (int off = 16; off < 64; off <<= 1) {
            float mo1 = __shfl_xor(m1, off);
            float mo2 = __shfl_xor(m2, off);
            int ko1 = __shfl_xor(k1, off);
            if (mo1 > m1 || (mo1 == m1 && ko1 < k1)) { m2 = fmaxf(m1, mo2); m1 = mo1; k1 = ko1; }
            else m2 = fmaxf(m2, mo1);
        }
        float s = 0.f;
        if (!book) {                                // prob never consumed for book 1
            #pragma unroll
            for (int ct = 0; ct < 4; ct++)
                #pragma unroll
                for (int j = 0; j < 4; j++) s += __expf(v[ct][j] - m1);
            #pragma unroll
            for (int off = 16; off < 64; off <<= 1) s += __shfl_xor(s, off);
        }
        if (lq == 0) {
            int vr = vr0 + waveY * 64 + rt * 16 + lm;
            float4 st = make_float4(m1, m2, __int_as_float(k1), s);
            part4[(size_t)vr * 8 + codeblk * 2 + waveX] = st;
        }
    }
}

// ---- combine the 8 per-slice partials of each row; write idx/prob; flag rescues
__global__ void combine_rows(const float* __restrict__ partials,
                             int* __restrict__ idx1, int* __restrict__ idx2,
                             float* __restrict__ prob,
                             int* __restrict__ rlist, int* __restrict__ cnt) {
    int vr = blockIdx.x * 256 + threadIdx.x;      // grid 296*256 = 75776 exact
    const float4* p = (const float4*)partials + (size_t)vr * 8;
    float sm[8], ss[8];
    float4 a = p[0];
    float m1 = a.x, m2 = a.y; int k1 = __float_as_int(a.z);
    sm[0] = a.x; ss[0] = a.w;
    #pragma unroll
    for (int j = 1; j < 8; j++) {
        float4 b = p[j];
        sm[j] = b.x; ss[j] = b.w;
        int kk = __float_as_int(b.z);
        if (b.x > m1 || (b.x == m1 && kk < k1)) { m2 = fmaxf(m1, b.y); m1 = b.x; k1 = kk; }
        else m2 = fmaxf(m2, b.x);
    }
    float S = 0.f;
    #pragma unroll
    for (int j = 0; j < 8; j++) S += ss[j] * __expf(sm[j] - m1);
    if (vr < 43008) { idx1[vr] = k1; prob[vr] = 1.0f / S; }
    else idx2[vr - 43008] = k1;
    if (m1 - m2 < EPS_V) { int pos = atomicAdd(cnt, 1); rlist[pos] = vr; }
}

// ---- exact fp64 recompute for flagged rows (idx + prob)
__launch_bounds__(256)
__global__ void rescue_exact(const float* __restrict__ feat,
                             const float* __restrict__ codebooks,
                             const double* __restrict__ cnd,
                             const int* __restrict__ rlist, const int* __restrict__ cnt,
                             int* __restrict__ idx1, int* __restrict__ idx2,
                             float* __restrict__ prob) {
    __shared__ double sfd[256];
    __shared__ double rv[4]; __shared__ int rk[4]; __shared__ double rs[4];
    __shared__ double gvmax; __shared__ int gkmax;
    int tid = threadIdx.x;
    int lane = tid & 63, wave = tid >> 6;
    int n = cnt[0];
    for (int e = blockIdx.x; e < n; e += gridDim.x) {
        int vr = rlist[e];
        int book = vr >= 43008;
        int fr = book ? vr - 43008 : vr;
        sfd[tid] = (double)feat[(size_t)fr * 256 + tid];
        __syncthreads();
        const float* cb = codebooks + (size_t)book * 131072;
        double vloc[2]; int kk[2];
        #pragma unroll
        for (int h = 0; h < 2; h++) {
            int k = h * 256 + tid;
            const float* cp = cb + (size_t)k * 256;
            double d0 = 0.0, d1 = 0.0, d2 = 0.0, d3 = 0.0;
            for (int c = 0; c < 256; c += 4) {
                float4 cv = *(const float4*)&cp[c];
                d0 = fma((double)cv.x, sfd[c],     d0);
                d1 = fma((double)cv.y, sfd[c + 1], d1);
                d2 = fma((double)cv.z, sfd[c + 2], d2);
                d3 = fma((double)cv.w, sfd[c + 3], d3);
            }
            double dot = (d0 + d1) + (d2 + d3);
            vloc[h] = 2.0 * dot - cnd[book * 512 + k];
            kk[h] = k;
        }
        double bv = vloc[0]; int bk = kk[0];
        if (vloc[1] > bv || (vloc[1] == bv && kk[1] < bk)) { bv = vloc[1]; bk = kk[1]; }
        #pragma unroll
        for (int off = 32; off; off >>= 1) {
            double vo = __shfl_xor(bv, off);
            int ko = __shfl_xor(bk, off);
            if (vo > bv || (vo == bv && ko < bk)) { bv = vo; bk = ko; }
        }
        if (lane == 0) { rv[wave] = bv; rk[wave] = bk; }
        __syncthreads();
        if (tid == 0) {
            double v0 = rv[0]; int K = rk[0];
            #pragma unroll
            for (int w = 1; w < 4; w++)
                if (rv[w] > v0 || (rv[w] == v0 && rk[w] < K)) { v0 = rv[w]; K = rk[w]; }
            gvmax = v0; gkmax = K;
        }
        __syncthreads();
        double vm = gvmax;
        double s = exp(vloc[0] - vm) + exp(vloc[1] - vm);
        #pragma unroll
        for (int off = 32; off; off >>= 1) s += __shfl_xor(s, off);
        if (lane == 0) rs[wave] = s;
        __syncthreads();
        if (tid == 0) {
            double S = ((rs[0] + rs[1]) + rs[2]) + rs[3];
            if (book) idx2[fr] = gkmax;
            else { idx1[vr] = gkmax; prob[vr] = (float)(1.0 / S); }
        }
        __syncthreads();
    }
}

// ---- fuse stage 1: decide per pixel; defer prob-fragile pixels to fuse2
__launch_bounds__(256)
__global__ void fuse1(const float* __restrict__ feat,
                      const float* __restrict__ prob,
                      const int* __restrict__ idx1, const int* __restrict__ idx2,
                      const float* __restrict__ codebooks,
                      float* __restrict__ out0, float* __restrict__ outZ,
                      float* __restrict__ outS,
                      int* __restrict__ dlist, int* __restrict__ cnt) {
    __shared__ int rsel_s[64], i1_s[64], i2_s[64], defer_s[64];
    int tid = threadIdx.x;
    int b = blockIdx.x >> 6, y = blockIdx.x & 63;

    if (tid < 64) {
        int x = tid;
        int r0 = (b * 64 + y) * 64 + x;
        int r1 = 32768 + (b * 32 + (y >> 1)) * 32 + (x >> 1);
        int r2 = 40960 + (b * 16 + (y >> 2)) * 16 + (x >> 2);
        float p0 = prob[r0], p1 = prob[r1], p2 = prob[r2];
        int rsel = r0; float best = p0;          // strict > keeps first-max
        if (p1 > best) { best = p1; rsel = r1; }
        if (p2 > best) { best = p2; rsel = r2; }
        float second = (rsel == r0) ? fmaxf(p1, p2)
                     : (rsel == r1) ? fmaxf(p0, p2) : fmaxf(p0, p1);
        int defer = (best - second < EPS_P_REL * best) ? 1 : 0;
        defer_s[x] = defer;
        if (defer) {
            int pos = atomicAdd(cnt + 1, 1);
            dlist[pos] = (b << 12) | (y << 6) | x;
            rsel_s[x] = r0; i1_s[x] = 0; i2_s[x] = 0;   // unused
        } else {
            int i1 = idx1[rsel], i2 = idx2[r0];
            rsel_s[x] = rsel; i1_s[x] = i1; i2_s[x] = i2;
            size_t zb = (size_t)b * 8192 + (size_t)y * 64 + x;
            outZ[zb] = (float)i1;
            outZ[zb + 4096] = (float)i2;
        }
    }
    __syncthreads();

    int x = tid & 63, cc = tid >> 6;
    int r0 = (b * 64 + y) * 64 + x;
    const float* e0p = feat + (size_t)r0 * 256;
    const float* e1p = feat + (size_t)rsel_s[x] * 256;
    const float* q1p = codebooks + (size_t)i1_s[x] * 256;
    const float* q2p = codebooks + (size_t)(512 + i2_s[x]) * 256;
    int defer = defer_s[x];
    for (int it = 0; it < 16; it++) {
        int c = it * 16 + cc * 4;
        float4 e0 = *(const float4*)&e0p[c];
        size_t o = (((size_t)b * 256 + c) * 64 + y) * 64 + x;
        out0[o]         = e0.x;                    // out0 never depends on decisions
        out0[o + 4096]  = e0.y;
        out0[o + 8192]  = e0.z;
        out0[o + 12288] = e0.w;
        if (!defer) {
            float4 e1 = *(const float4*)&e1p[c];
            float4 q1 = *(const float4*)&q1p[c];
            float4 q2 = *(const float4*)&q2p[c];
            float ef, qf;
            ef = (e1.x + e0.x) * 0.5f; qf = (q1.x + q2.x) * 0.5f; outS[o]         = ef + (qf - ef);
            ef = (e1.y + e0.y) * 0.5f; qf = (q1.y + q2.y) * 0.5f; outS[o + 4096]  = ef + (qf - ef);
            ef = (e1.z + e0.z) * 0.5f; qf = (q1.z + q2.z) * 0.5f; outS[o + 8192]  = ef + (qf - ef);
            ef = (e1.w + e0.w) * 0.5f; qf = (q1.w + q2.w) * 0.5f; outS[o + 12288] = ef + (qf - ef);
        }
    }
}

// ---- fuse stage 2: deferred pixels, full fp64 (3 rows x 512 codes each)
__launch_bounds__(256)
__global__ void fuse2(const float* __restrict__ feat,
                      const float* __restrict__ codebooks,
                      const double* __restrict__ cnd,
                      const int* __restrict__ idx2,
                      const int* __restrict__ dlist, const int* __restrict__ cnt,
                      float* __restrict__ outZ, float* __restrict__ outS) {
    __shared__ double sfd[256];
    __shared__ double rv[4]; __shared__ int rk[4]; __shared__ double rs[4];
    __shared__ double gvmax;
    __shared__ double pRes[3]; __shared__ int kRes[3];
    __shared__ int selS, i2S;
    int tid = threadIdx.x;
    int lane = tid & 63, wave = tid >> 6;
    int n = cnt[1];
    for (int e = blockIdx.x; e < n; e += gridDim.x) {
        int px = dlist[e];
        int b = px >> 12, y = (px >> 6) & 63, x = px & 63;
        int r0 = (b * 64 + y) * 64 + x;
        int r1 = 32768 + (b * 32 + (y >> 1)) * 32 + (x >> 1);
        int r2 = 40960 + (b * 16 + (y >> 2)) * 16 + (x >> 2);
        int rows[3] = {r0, r1, r2};
        for (int s3 = 0; s3 < 3; s3++) {
            sfd[tid] = (double)feat[(size_t)rows[s3] * 256 + tid];
            __syncthreads();
            double vloc[2];
            #pragma unroll
            for (int h = 0; h < 2; h++) {
                int k = h * 256 + tid;
                const float* cp = codebooks + (size_t)k * 256;
                double d0 = 0.0, d1 = 0.0, d2 = 0.0, d3 = 0.0;
                for (int c = 0; c < 256; c += 4) {
                    float4 cv = *(const float4*)&cp[c];
                    d0 = fma((double)cv.x, sfd[c],     d0);
                    d1 = fma((double)cv.y, sfd[c + 1], d1);
                    d2 = fma((double)cv.z, sfd[c + 2], d2);
                    d3 = fma((double)cv.w, sfd[c + 3], d3);
                }
                double dot = (d0 + d1) + (d2 + d3);
                vloc[h] = 2.0 * dot - cnd[k];
            }
            double bv = vloc[0]; int bk = tid;
            if (vloc[1] > bv) { bv = vloc[1]; bk = tid + 256; }
            #pragma unroll
            for (int off = 32; off; off >>= 1) {
                double vo = __shfl_xor(bv, off);
                int ko = __shfl_xor(bk, off);
                if (vo > bv || (vo == bv && ko < bk)) { bv = vo; bk = ko; }
            }
            if (lane == 0) { rv[wave] = bv; rk[wave] = bk; }
            __syncthreads();
            if (tid == 0) {
                double v0 = rv[0]; int K = rk[0];
                #pragma unroll
                for (int w = 1; w < 4; w++)
                    if (rv[w] > v0 || (rv[w] == v0 && rk[w] < K)) { v0 = rv[w]; K = rk[w]; }
                gvmax = v0; kRes[s3] = K;
            }
            __syncthreads();
            double vm = gvmax;
            double s = exp(vloc[0] - vm) + exp(vloc[1] - vm);
            #pragma unroll
            for (int off = 32; off; off >>= 1) s += __shfl_xor(s, off);
            if (lane == 0) rs[wave] = s;
            __syncthreads();
            if (tid == 0) pRes[s3] = 1.0 / (((rs[0] + rs[1]) + rs[2]) + rs[3]);
            __syncthreads();
        }
        if (tid == 0) {
            int sel = 0; double best = pRes[0];
            if (pRes[1] > best) { best = pRes[1]; sel = 1; }
            if (pRes[2] > best) { best = pRes[2]; sel = 2; }
            selS = sel;
            int i2 = idx2[r0];
            i2S = i2;
            size_t zb = (size_t)b * 8192 + (size_t)y * 64 + x;
            outZ[zb] = (float)kRes[sel];
            outZ[zb + 4096] = (float)i2;
        }
        __syncthreads();
        int sel = selS;
        int c = tid;
        float e0 = feat[(size_t)r0 * 256 + c];
        float e1 = feat[(size_t)rows[sel] * 256 + c];
        float q1 = codebooks[(size_t)kRes[sel] * 256 + c];
        float q2 = codebooks[(size_t)(512 + i2S) * 256 + c];
        float ef = (e1 + e0) * 0.5f;
        float qf = (q1 + q2) * 0.5f;
        size_t o = (((size_t)b * 256 + c) * 64 + y) * 64 + x;
        outS[o] = ef + (qf - ef);
        __syncthreads();
    }
}

extern "C" void kernel_launch(void* const* d_in, const int* in_sizes, int n_in,
                              void* d_out, int out_size, void* d_ws, size_t ws_size,
                              hipStream_t stream) {
    (void)in_sizes; (void)n_in; (void)out_size; (void)ws_size;
    const float* image     = (const float*)d_in[0];   // [8,3,256,256]
    const float* conv_w    = (const float*)d_in[1];   // [256,3,4,4]
    const float* conv_b    = (const float*)d_in[2];   // [256]
    const float* codebooks = (const float*)d_in[3];   // [4,512,256]

    float*  ws    = (float*)d_ws;
    float*  feat  = ws + FEAT_OFF;
    float*  parts = ws + PART_OFF;
    float*  prob  = ws + PROB_OFF;
    int*    idx1  = (int*)(ws + IDX1_OFF);
    int*    idx2  = (int*)(ws + IDX2_OFF);
    float*  cnf   = ws + CNF_OFF;
    double* cnd   = (double*)(ws + CND_OFF);
    unsigned short* cbs = (unsigned short*)(ws + CBS_OFF);
    float*  img1  = ws + IMG1_OFF;
    float*  img2  = ws + IMG2_OFF;
    int*    rlist = (int*)(ws + RLIST_OFF);
    int*    dlist = (int*)(ws + DLIST_OFF);
    int*    cnt   = (int*)(ws + CNT_OFF);

    float* out  = (float*)d_out;
    float* out0 = out;
    float* outZ = out + 8388608;
    float* outS = out + 8454144;
    // d_out doubles as scratch for the bf16 feat planes until fuse1 runs;
    // fuse1/fuse2 rewrite every output byte afterwards.
    unsigned short* featbf = (unsigned short*)d_out;

    prep<<<3200, 256, 0, stream>>>(image, codebooks, img1, img2, cnd, cnf, cbs, cnt);
    encode_all<<<896, 256, 0, stream>>>(image, img1, img2, conv_w, conv_b, feat, featbf);
    match_bulk<<<2368, 256, 0, stream>>>(featbf, cbs, cnf, parts);
    combine_rows<<<296, 256, 0, stream>>>(parts, idx1, idx2, prob, rlist, cnt);
    rescue_exact<<<1024, 256, 0, stream>>>(feat, codebooks, cnd, rlist, cnt, idx1, idx2, prob);
    fuse1<<<512, 256, 0, stream>>>(feat, prob, idx1, idx2, codebooks, out0, outZ, outS, dlist, cnt);
    fuse2<<<512, 256, 0, stream>>>(feat, codebooks, cnd, idx2, dlist, cnt, outZ, outS);
}

// Round 6
// 281.207 us; speedup vs baseline: 1.5134x; 1.0091x over previous
//
#include <hip/hip_runtime.h>
#include <math.h>

// ---------------------------------------------------------------------------
// VQVAEZMultiScale round 10 — dependent-MFMA de-stall + encode/fuse1 splits.
//   Round-9 diagnosis: occupancy 17->28% bought nothing (73 vs 69 us) ->
//   match_bulk is per-wave-latency-bound, not TLP-bound. DOMFMA issued the 3
//   passes of each accumulator back-to-back (in-order issue stalls on the
//   dependent pairs). ~210us now outside match_bulk (encode serial x-loop,
//   fuse1 scattered-load latency at low block count).
//   Changes:
//     * match_bulk DOMFMA: 3 sweeps of 16 INDEPENDENT MFMAs (pass-major
//       order) instead of 16 dependent triples. Per-acc op order unchanged.
//     * encode_all: scale-0 rows split into x-halves -> grid 1408, serial
//       depth 64->32 positions, patch LDS halved.
//     * fuse1: 2 channel-half blocks per (b,y) -> grid 1024; decisions
//       computed redundantly, outZ/dlist writes gated to half 0.
// Workspace layout (float units), total ~57.7 MB (unchanged):
//   feat   [43008][256] f32        @ 0
//   partials [75776][8] float4     @ 11010048
//   prob   f32[43008]              @ 13434880
//   idx1   int[43008]              @ 13477888
//   idx2   int[32768]              @ 13520896
//   cnf    f32[1024]               @ 13553664
//   cnd    double[1024]            @ 13554688
//   cbs    bf16 tiled [book][split][codeblk][kc][128][32] @ 13556736
//   img1   [8][3][128][128]        @ 13818880
//   img2   [8][3][64][64]          @ 14212096
//   rlist  int[75776]              @ 14310400
//   dlist  int[32768]              @ 14386176
//   cnt    int[2]                  @ 14418944
// d_out scratch reuse (before fuse1): bf16 feat planes
//   [split][336 rowblk][8 kc][128][32] ushort, 22,020,096 ushorts = 44 MB.
// Output: out0 @0, zidx @8388608 (as float), ste0 @8454144 (all f32, NCHW)
// ---------------------------------------------------------------------------

#define FEAT_OFF   0
#define PART_OFF   11010048
#define PROB_OFF   13434880
#define IDX1_OFF   13477888
#define IDX2_OFF   13520896
#define CNF_OFF    13553664
#define CND_OFF    13554688
#define CBS_OFF    13556736
#define IMG1_OFF   13818880
#define IMG2_OFF   14212096
#define RLIST_OFF  14310400
#define DLIST_OFF  14386176
#define CNT_OFF    14418944

#define PLANE_STRIDE 11010048   // ushorts per split plane (336*8*128*32)

#define EPS_V 1e-3f          // v abs error <= ~3e-5 worst-case -> 30x margin
#define EPS_P_REL 2e-3f      // prob rel error <= ~1e-4 -> 20x margin

typedef __attribute__((ext_vector_type(8))) short short8;
typedef __attribute__((ext_vector_type(4))) float f32x4;
typedef __attribute__((ext_vector_type(4))) unsigned int u32x4;

__device__ inline unsigned short f2bf(float x) {
    unsigned u = __float_as_uint(x);
    return (unsigned short)((u + 0x7FFFu + ((u >> 16) & 1u)) >> 16);
}
__device__ inline float bf2f(unsigned short h) {
    return __uint_as_float(((unsigned)h) << 16);
}
// row-dependent channel-quad swizzle: 2-way max bank aliasing on b128 reads
__device__ inline int rswz(int row) { return (row & 3) ^ ((row >> 2) & 3); }

// global -> LDS direct copy, 16 B per lane. LDS dest must be wave-uniform.
__device__ inline void glds16(const unsigned short* g, unsigned short* l) {
    __builtin_amdgcn_global_load_lds(
        (const __attribute__((address_space(1))) void*)g,
        (__attribute__((address_space(3))) void*)l, 16, 0, 0);
}

// ---- fused prep: zero_cnt + bilinear ds (2 scales) + code norms + cb split
__launch_bounds__(256)
__global__ void prep(const float* __restrict__ image,
                     const float* __restrict__ codebooks,
                     float* __restrict__ img1, float* __restrict__ img2,
                     double* __restrict__ cnd, float* __restrict__ cnf,
                     unsigned short* __restrict__ cbs, int* __restrict__ cnt) {
    int bid = blockIdx.x, tid = threadIdx.x;
    if (bid == 0 && tid < 2) cnt[tid] = 0;
    if (bid < 1536) {                       // ds scale 1: 128x128, o=0, f=2
        int i = bid * 256 + tid;            // 8*3*128*128 = 393216 exact
        int x = i & 127;
        int t = i >> 7;
        int y = t & 127;
        int bc = t >> 7;
        const float* base = image + ((size_t)bc * 256 + (size_t)(y * 2)) * 256;
        int cx = x * 2;
        float v00 = base[cx],     v10 = base[256 + cx];
        float v01 = base[cx + 1], v11 = base[256 + cx + 1];
        img1[i] = ((v00 + v10) * 0.5f + (v01 + v11) * 0.5f) * 0.5f;
    } else if (bid < 1920) {                // ds scale 2: 64x64, o=1, f=4
        int i = (bid - 1536) * 256 + tid;   // 8*3*64*64 = 98304 exact
        int x = i & 63;
        int t = i >> 6;
        int y = t & 63;
        int bc = t >> 6;
        const float* base = image + ((size_t)bc * 256 + (size_t)(y * 4 + 1)) * 256;
        int cx = x * 4 + 1;
        float v00 = base[cx],     v10 = base[256 + cx];
        float v01 = base[cx + 1], v11 = base[256 + cx + 1];
        img2[i] = ((v00 + v10) * 0.5f + (v01 + v11) * 0.5f) * 0.5f;
    } else if (bid < 2176) {                // code norms: 4 rows/block, 1 wave/row
        int row = (bid - 1920) * 4 + (tid >> 6);
        int lane = tid & 63;
        const float* p = codebooks + (size_t)row * 256;
        double s = 0.0;
        for (int c = lane; c < 256; c += 64) {
            double v = (double)p[c];
            s = fma(v, v, s);
        }
        #pragma unroll
        for (int off = 32; off; off >>= 1) s += __shfl_down(s, off);
        if (lane == 0) { cnd[row] = s; cnf[row] = (float)s; }
    } else {                                // split_cb: tiled+swizzled bf16 planes
        int i = (bid - 2176) * 256 + tid;   // 2*512*256 = 262144 exact
        int book = i >> 17, rem = i & 131071;
        int code = rem >> 8, ch = rem & 255;
        float c = codebooks[(size_t)book * 131072 + rem];
        unsigned short h0 = f2bf(c);
        unsigned short h1 = f2bf(c - bf2f(h0));
        int codeblk = code >> 7, row = code & 127;
        int kc = ch >> 5, q = (ch >> 3) & 3, j = ch & 7;
        int qs = q ^ rswz(row);
        size_t off = ((((size_t)(book * 2) * 4 + codeblk) * 8 + kc) * 128 + row) * 32 + qs * 8 + j;
        cbs[off] = h0;                      // split 0
        cbs[off + 4 * 32768] = h1;          // split 1
    }
}

// ---- stride-4 patchify conv, all 3 scales; scale-0 rows split into x-halves.
//      featbf flushed every 4 positions by all 256 threads (uint4 stores).
__launch_bounds__(256)
__global__ void encode_all(const float* __restrict__ image,
                           const float* __restrict__ img1,
                           const float* __restrict__ img2,
                           const float* __restrict__ w,
                           const float* __restrict__ bias,
                           float* __restrict__ feat,
                           unsigned short* __restrict__ featbf) {
    __shared__ float patch[12 * 128];                       // <=128 cols per block
    __shared__ __align__(16) unsigned short pk[2][4][2][256];  // [buf][pos][plane][ch]
    int bid = blockIdx.x;
    const float* img; int Hout, rowbase, local, xbase, npos, Wimg, WL, colbase;
    if (bid < 1024) {        // scale 0: 512 rows x 2 x-halves
        img = image; Hout = 64; rowbase = 0;
        local = bid >> 1; int half = bid & 1;
        xbase = half * 32; npos = 32; Wimg = 256; WL = 128; colbase = half * 128;
    } else if (bid < 1280) { // scale 1: 256 rows
        img = img1; Hout = 32; rowbase = 32768;
        local = bid - 1024; xbase = 0; npos = 32; Wimg = 128; WL = 128; colbase = 0;
    } else {                 // scale 2: 128 rows
        img = img2; Hout = 16; rowbase = 40960;
        local = bid - 1280; xbase = 0; npos = 16; Wimg = 64; WL = 64; colbase = 0;
    }
    int Wout = Hout;
    int tid = threadIdx.x;
    int b = local / Hout, y = local % Hout;
    int Himg = Hout * 4;

    const float* ibase = img + (size_t)b * 3 * Himg * Wimg;
    int nload = 12 * WL;
    for (int i = tid; i < nload; i += 256) {
        int cl = i % WL, r = i / WL;         // r = ci*4 + kh
        int ci = r >> 2, kh = r & 3;
        patch[r * WL + cl] = ibase[((size_t)ci * Himg + 4 * y + kh) * Wimg + colbase + cl];
    }
    float wr[48];
    #pragma unroll
    for (int j = 0; j < 48; j++) wr[j] = w[tid * 48 + j];
    float bv = bias[tid];
    __syncthreads();

    // flush mapping: 256 threads = 4 pos x 2 planes x 8 kc x 4 quad-groups
    int fp = tid >> 6, fwp = (tid >> 5) & 1, fkc = (tid >> 2) & 7, fwg = tid & 3;
    int rb = rowbase + (b * Hout + y) * Wout + xbase;
    for (int x0 = 0; x0 < npos; x0 += 4) {
        int buf = (x0 >> 2) & 1;
        #pragma unroll
        for (int p = 0; p < 4; p++) {
            int xl = x0 + p;                 // local position; patch col = 4*xl
            float acc = 0.f;
            #pragma unroll
            for (int ci = 0; ci < 3; ci++)
                #pragma unroll
                for (int kh = 0; kh < 4; kh++) {
                    const float* pr = &patch[(ci * 4 + kh) * WL + 4 * xl];
                    #pragma unroll
                    for (int kw = 0; kw < 4; kw++)
                        acc = fmaf(pr[kw], wr[ci * 16 + kh * 4 + kw], acc);
                }
            float val = acc + bv;
            feat[(size_t)(rb + xl) * 256 + tid] = val;
            unsigned short hi = f2bf(val);
            pk[buf][p][0][tid] = hi;
            pk[buf][p][1][tid] = f2bf(val - bf2f(hi));
        }
        __syncthreads();                   // dbuf: one barrier per 4 positions
        {
            int r = rb + x0 + fp;
            int rowblk = r >> 7, rrow = r & 127;
            int ch0 = fkc * 32 + ((fwg ^ rswz(rrow)) << 3);
            uint4 v = *(const uint4*)&pk[buf][fp][fwp][ch0];
            size_t off = (((size_t)rowblk * 8 + fkc) * 128 + rrow) * 32 + fwg * 8
                       + (size_t)fwp * PLANE_STRIDE;
            *(uint4*)&featbf[off] = v;
        }
    }
}

// ---- bulk MFMA match. Block: 128 virtual-rows x 128 codes; grid 592x4.
//      A0/A1/B0 via glds16 double-buffer; B1 register-staged (inline asm).
//      Counted vmcnt: 10 vmem ops per kc-tile, steady wait vmcnt(10).
//      MFMA emitted pass-major: 3 sweeps of 16 independent ops (no
//      dependent back-to-back stalls on in-order issue).
__launch_bounds__(256, 3)
__global__ void match_bulk(const unsigned short* __restrict__ featbf,
                           const unsigned short* __restrict__ cbs,
                           const float* __restrict__ cnf,
                           float* __restrict__ partials) {
    __shared__ unsigned short A0s[2][4096], A1s[2][4096], B0s[2][4096];
    // bijective XCD swizzle: 2368 = 8*296; co-locate the 4 codeblk blocks of a
    // rowtile on one XCD L2 so the feat tile is fetched once, not 4x.
    int bid0 = blockIdx.x;
    int bid = (bid0 & 7) * 296 + (bid0 >> 3);
    int codeblk = bid & 3, rowtile = bid >> 2;     // 4 x 592
    int book = (rowtile >= 336) ? 1 : 0;
    int rowblk = book ? rowtile - 336 : rowtile;
    int vr0 = rowtile * 128;
    int tid = threadIdx.x;
    int wid = tid >> 6, l = tid & 63;
    int waveY = wid & 1, waveX = wid >> 1;
    int lm = l & 15, lq = l >> 4;
    int slot = lq ^ rswz(lm);                      // lane-constant swizzled quad
    int wlds = wid * 512;                          // ushort units, 1 KiB chunks

    // acc[ct][rt]: row (lq*4+j) = code within ct-tile, col (lm) = feat row
    f32x4 acc[4][4];
    #pragma unroll
    for (int ct = 0; ct < 4; ct++)
        #pragma unroll
        for (int rt = 0; rt < 4; rt++) acc[ct][rt] = (f32x4)0.0f;

    const unsigned short* gA0 = featbf + (size_t)rowblk * 32768 + tid * 8;
    const unsigned short* gA1 = gA0 + PLANE_STRIDE;
    const unsigned short* gB0 = cbs + ((size_t)(book * 8) + codeblk) * 32768 + tid * 8;
    // per-lane B1 fragment base (matches old LDS-path layout exactly)
    const unsigned short* gB1f = cbs + ((size_t)(book * 8) + codeblk) * 32768 + 131072
                               + ((waveX * 64 + lm) * 32 + slot * 8);

    auto STAGE6 = [&](int buf, int kc) {           // 6 glds16 = 6 vmcnt units
        const unsigned short* ga0 = gA0 + kc * 4096;
        const unsigned short* ga1 = gA1 + kc * 4096;
        const unsigned short* gb0 = gB0 + kc * 4096;
        #pragma unroll
        for (int i = 0; i < 2; i++) {
            glds16(ga0 + i * 2048, &A0s[buf][i * 2048 + wlds]);
            glds16(ga1 + i * 2048, &A1s[buf][i * 2048 + wlds]);
            glds16(gb0 + i * 2048, &B0s[buf][i * 2048 + wlds]);
        }
    };

    u32x4 qA[4], qB[4];                            // 2 rotating B1 reg sets
    auto B1LOAD = [&](u32x4 (&q)[4], int kc) {     // 4 vmcnt units
        const unsigned short* p = gB1f + (size_t)kc * 4096;
        // "=&v" early-clobber: async VMEM dest must NOT alias the 64-bit
        // address pair (round-8 fault) nor each other.
        asm volatile(
            "global_load_dwordx4 %0, %4, off\n\t"
            "global_load_dwordx4 %1, %4, off offset:1024\n\t"
            "global_load_dwordx4 %2, %4, off offset:2048\n\t"
            "global_load_dwordx4 %3, %4, off offset:3072"
            : "=&v"(q[0]), "=&v"(q[1]), "=&v"(q[2]), "=&v"(q[3])
            : "v"(p)
            : "memory");
    };

    short8 a0[4], a1[4], b0[4];
    auto LOADFRAG = [&](int cur) {                 // 12 ds_read_b128
        #pragma unroll
        for (int t = 0; t < 4; t++) {
            int ra = (waveY * 64 + t * 16 + lm) * 32 + slot * 8;
            int rbx = (waveX * 64 + t * 16 + lm) * 32 + slot * 8;
            a0[t] = *(const short8*)&A0s[cur][ra];
            a1[t] = *(const short8*)&A1s[cur][ra];
            b0[t] = *(const short8*)&B0s[cur][rbx];
        }
    };
    auto DOMFMA = [&](u32x4 (&q)[4]) {
        short8 b1v[4];
        #pragma unroll
        for (int ct = 0; ct < 4; ct++) __builtin_memcpy(&b1v[ct], &q[ct], 16);
        __builtin_amdgcn_s_setprio(1);
        // pass-major: 16 independent MFMAs per sweep; per-acc order is still
        // b0*a0 -> b1*a0 -> b0*a1 (bit-identical accumulation).
        #pragma unroll
        for (int ct = 0; ct < 4; ct++)
            #pragma unroll
            for (int rt = 0; rt < 4; rt++)
                acc[ct][rt] = __builtin_amdgcn_mfma_f32_16x16x32_bf16(b0[ct], a0[rt], acc[ct][rt], 0, 0, 0);
        #pragma unroll
        for (int ct = 0; ct < 4; ct++)
            #pragma unroll
            for (int rt = 0; rt < 4; rt++)
                acc[ct][rt] = __builtin_amdgcn_mfma_f32_16x16x32_bf16(b1v[ct], a0[rt], acc[ct][rt], 0, 0, 0);
        #pragma unroll
        for (int ct = 0; ct < 4; ct++)
            #pragma unroll
            for (int rt = 0; rt < 4; rt++)
                acc[ct][rt] = __builtin_amdgcn_mfma_f32_16x16x32_bf16(b0[ct], a1[rt], acc[ct][rt], 0, 0, 0);
        __builtin_amdgcn_s_setprio(0);
    };

    // prologue: tiles 0 and 1 fully issued (tile-ordered: 6g+4b, 6g+4b)
    STAGE6(0, 0); B1LOAD(qA, 0);
    STAGE6(1, 1); B1LOAD(qB, 1);

    // steady state: wait vmcnt(10) = tile kc landed (tile kc+1 still in flight)
#define MB_STEP(KC, QQ)                                                    \
    do {                                                                   \
        asm volatile("s_waitcnt vmcnt(10)" ::: "memory");                  \
        __builtin_amdgcn_s_barrier();                                      \
        __builtin_amdgcn_sched_barrier(0);                                 \
        LOADFRAG((KC) & 1);                                                \
        asm volatile("s_waitcnt lgkmcnt(0)" ::: "memory");                 \
        __builtin_amdgcn_sched_barrier(0);                                 \
        __builtin_amdgcn_s_barrier();                                      \
        __builtin_amdgcn_sched_barrier(0);                                 \
        STAGE6((KC) & 1, (KC) + 2);                                        \
        DOMFMA(QQ);                                                        \
        B1LOAD(QQ, (KC) + 2);                                              \
    } while (0)

    MB_STEP(0, qA); MB_STEP(1, qB); MB_STEP(2, qA);
    MB_STEP(3, qB); MB_STEP(4, qA); MB_STEP(5, qB);
#undef MB_STEP

    // kc = 6: tile 7's 10 ops still in flight; no further staging
    asm volatile("s_waitcnt vmcnt(10)" ::: "memory");
    __builtin_amdgcn_s_barrier();
    __builtin_amdgcn_sched_barrier(0);
    LOADFRAG(0);
    asm volatile("s_waitcnt lgkmcnt(0)" ::: "memory");
    __builtin_amdgcn_sched_barrier(0);
    DOMFMA(qA);
    // kc = 7: drain
    asm volatile("s_waitcnt vmcnt(0)" ::: "memory");
    __builtin_amdgcn_s_barrier();
    __builtin_amdgcn_sched_barrier(0);
    LOADFRAG(1);
    asm volatile("s_waitcnt lgkmcnt(0)" ::: "memory");
    __builtin_amdgcn_sched_barrier(0);
    DOMFMA(qB);

    // per-thread codes: kbase + ct*16 + j, all 16 in-register
    int kbase = codeblk * 128 + waveX * 64 + lq * 4;
    float4 cnv4[4];
    #pragma unroll
    for (int ct = 0; ct < 4; ct++)
        cnv4[ct] = *(const float4*)&cnf[book * 512 + kbase + ct * 16];
    float4* part4 = (float4*)partials;

    #pragma unroll
    for (int rt = 0; rt < 4; rt++) {
        float v[4][4];
        #pragma unroll
        for (int ct = 0; ct < 4; ct++) {
            v[ct][0] = 2.0f * acc[ct][rt][0] - cnv4[ct].x;
            v[ct][1] = 2.0f * acc[ct][rt][1] - cnv4[ct].y;
            v[ct][2] = 2.0f * acc[ct][rt][2] - cnv4[ct].z;
            v[ct][3] = 2.0f * acc[ct][rt][3] - cnv4[ct].w;
        }
        // in-thread argmax over 16 codes (ascending index: strict > keeps first)
        float m1 = v[0][0], m2 = -3.4e38f;
        int k1 = kbase;
        #pragma unroll
        for (int ct = 0; ct < 4; ct++)
            #pragma unroll
            for (int j = 0; j < 4; j++) {
                if (ct == 0 && j == 0) continue;
                float val = v[ct][j];
                if (val > m1) { m2 = m1; m1 = val; k1 = kbase + ct * 16 + j; }
                else m2 = fmaxf(m2, val);
            }
        // cross-lane over lq (lanes 16 apart): 2 butterfly steps
        #pragma unroll
        for (int off = 16; off < 64; off <<= 1) {
            float mo1 = __shfl_xor(m1, off);
            float mo2 = __shfl_xor(m2, off);
            int ko1 = __shfl_xor(k1, off);
            if (mo1 > m1 || (mo1 == m1 && ko1 < k1)) { m2 = fmaxf(m1, mo2); m1 = mo1; k1 = ko1; }
            else m2 = fmaxf(m2, mo1);
        }
        float s = 0.f;
        if (!book) {                                // prob never consumed for book 1
            #pragma unroll
            for (int ct = 0; ct < 4; ct++)
                #pragma unroll
                for (int j = 0; j < 4; j++) s += __expf(v[ct][j] - m1);
            #pragma unroll
            for (int off = 16; off < 64; off <<= 1) s += __shfl_xor(s, off);
        }
        if (lq == 0) {
            int vr = vr0 + waveY * 64 + rt * 16 + lm;
            float4 st = make_float4(m1, m2, __int_as_float(k1), s);
            part4[(size_t)vr * 8 + codeblk * 2 + waveX] = st;
        }
    }
}

// ---- combine the 8 per-slice partials of each row; write idx/prob; flag rescues
__global__ void combine_rows(const float* __restrict__ partials,
                             int* __restrict__ idx1, int* __restrict__ idx2,
                             float* __restrict__ prob,
                             int* __restrict__ rlist, int* __restrict__ cnt) {
    int vr = blockIdx.x * 256 + threadIdx.x;      // grid 296*256 = 75776 exact
    const float4* p = (const float4*)partials + (size_t)vr * 8;
    float sm[8], ss[8];
    float4 a = p[0];
    float m1 = a.x, m2 = a.y; int k1 = __float_as_int(a.z);
    sm[0] = a.x; ss[0] = a.w;
    #pragma unroll
    for (int j = 1; j < 8; j++) {
        float4 b = p[j];
        sm[j] = b.x; ss[j] = b.w;
        int kk = __float_as_int(b.z);
        if (b.x > m1 || (b.x == m1 && kk < k1)) { m2 = fmaxf(m1, b.y); m1 = b.x; k1 = kk; }
        else m2 = fmaxf(m2, b.x);
    }
    float S = 0.f;
    #pragma unroll
    for (int j = 0; j < 8; j++) S += ss[j] * __expf(sm[j] - m1);
    if (vr < 43008) { idx1[vr] = k1; prob[vr] = 1.0f / S; }
    else idx2[vr - 43008] = k1;
    if (m1 - m2 < EPS_V) { int pos = atomicAdd(cnt, 1); rlist[pos] = vr; }
}

// ---- exact fp64 recompute for flagged rows (idx + prob)
__launch_bounds__(256)
__global__ void rescue_exact(const float* __restrict__ feat,
                             const float* __restrict__ codebooks,
                             const double* __restrict__ cnd,
                             const int* __restrict__ rlist, const int* __restrict__ cnt,
                             int* __restrict__ idx1, int* __restrict__ idx2,
                             float* __restrict__ prob) {
    __shared__ double sfd[256];
    __shared__ double rv[4]; __shared__ int rk[4]; __shared__ double rs[4];
    __shared__ double gvmax; __shared__ int gkmax;
    int tid = threadIdx.x;
    int lane = tid & 63, wave = tid >> 6;
    int n = cnt[0];
    for (int e = blockIdx.x; e < n; e += gridDim.x) {
        int vr = rlist[e];
        int book = vr >= 43008;
        int fr = book ? vr - 43008 : vr;
        sfd[tid] = (double)feat[(size_t)fr * 256 + tid];
        __syncthreads();
        const float* cb = codebooks + (size_t)book * 131072;
        double vloc[2]; int kk[2];
        #pragma unroll
        for (int h = 0; h < 2; h++) {
            int k = h * 256 + tid;
            const float* cp = cb + (size_t)k * 256;
            double d0 = 0.0, d1 = 0.0, d2 = 0.0, d3 = 0.0;
            for (int c = 0; c < 256; c += 4) {
                float4 cv = *(const float4*)&cp[c];
                d0 = fma((double)cv.x, sfd[c],     d0);
                d1 = fma((double)cv.y, sfd[c + 1], d1);
                d2 = fma((double)cv.z, sfd[c + 2], d2);
                d3 = fma((double)cv.w, sfd[c + 3], d3);
            }
            double dot = (d0 + d1) + (d2 + d3);
            vloc[h] = 2.0 * dot - cnd[book * 512 + k];
            kk[h] = k;
        }
        double bv = vloc[0]; int bk = kk[0];
        if (vloc[1] > bv || (vloc[1] == bv && kk[1] < bk)) { bv = vloc[1]; bk = kk[1]; }
        #pragma unroll
        for (int off = 32; off; off >>= 1) {
            double vo = __shfl_xor(bv, off);
            int ko = __shfl_xor(bk, off);
            if (vo > bv || (vo == bv && ko < bk)) { bv = vo; bk = ko; }
        }
        if (lane == 0) { rv[wave] = bv; rk[wave] = bk; }
        __syncthreads();
        if (tid == 0) {
            double v0 = rv[0]; int K = rk[0];
            #pragma unroll
            for (int w = 1; w < 4; w++)
                if (rv[w] > v0 || (rv[w] == v0 && rk[w] < K)) { v0 = rv[w]; K = rk[w]; }
            gvmax = v0; gkmax = K;
        }
        __syncthreads();
        double vm = gvmax;
        double s = exp(vloc[0] - vm) + exp(vloc[1] - vm);
        #pragma unroll
        for (int off = 32; off; off >>= 1) s += __shfl_xor(s, off);
        if (lane == 0) rs[wave] = s;
        __syncthreads();
        if (tid == 0) {
            double S = ((rs[0] + rs[1]) + rs[2]) + rs[3];
            if (book) idx2[fr] = gkmax;
            else { idx1[vr] = gkmax; prob[vr] = (float)(1.0 / S); }
        }
        __syncthreads();
    }
}

// ---- fuse stage 1: decide per pixel; defer prob-fragile pixels to fuse2.
//      2 channel-half blocks per (b,y); outZ/dlist writes gated to half 0.
__launch_bounds__(256)
__global__ void fuse1(const float* __restrict__ feat,
                      const float* __restrict__ prob,
                      const int* __restrict__ idx1, const int* __restrict__ idx2,
                      const float* __restrict__ codebooks,
                      float* __restrict__ out0, float* __restrict__ outZ,
                      float* __restrict__ outS,
                      int* __restrict__ dlist, int* __restrict__ cnt) {
    __shared__ int rsel_s[64], i1_s[64], i2_s[64], defer_s[64];
    int tid = threadIdx.x;
    int bid = blockIdx.x;
    int chh = bid & 1;                       // channel half
    int rowid = bid >> 1;
    int b = rowid >> 6, y = rowid & 63;

    if (tid < 64) {
        int x = tid;
        int r0 = (b * 64 + y) * 64 + x;
        int r1 = 32768 + (b * 32 + (y >> 1)) * 32 + (x >> 1);
        int r2 = 40960 + (b * 16 + (y >> 2)) * 16 + (x >> 2);
        float p0 = prob[r0], p1 = prob[r1], p2 = prob[r2];
        int rsel = r0; float best = p0;          // strict > keeps first-max
        if (p1 > best) { best = p1; rsel = r1; }
        if (p2 > best) { best = p2; rsel = r2; }
        float second = (rsel == r0) ? fmaxf(p1, p2)
                     : (rsel == r1) ? fmaxf(p0, p2) : fmaxf(p0, p1);
        int defer = (best - second < EPS_P_REL * best) ? 1 : 0;
        defer_s[x] = defer;
        if (defer) {
            if (chh == 0) {                  // half 0 owns list append + outZ
                int pos = atomicAdd(cnt + 1, 1);
                dlist[pos] = (b << 12) | (y << 6) | x;
            }
            rsel_s[x] = r0; i1_s[x] = 0; i2_s[x] = 0;   // unused
        } else {
            int i1 = idx1[rsel], i2 = idx2[r0];
            rsel_s[x] = rsel; i1_s[x] = i1; i2_s[x] = i2;
            if (chh == 0) {
                size_t zb = (size_t)b * 8192 + (size_t)y * 64 + x;
                outZ[zb] = (float)i1;
                outZ[zb + 4096] = (float)i2;
            }
        }
    }
    __syncthreads();

    int x = tid & 63, cc = tid >> 6;
    int r0 = (b * 64 + y) * 64 + x;
    const float* e0p = feat + (size_t)r0 * 256;
    const float* e1p = feat + (size_t)rsel_s[x] * 256;
    const float* q1p = codebooks + (size_t)i1_s[x] * 256;
    const float* q2p = codebooks + (size_t)(512 + i2_s[x]) * 256;
    int defer = defer_s[x];
    for (int it = 0; it < 8; it++) {
        int c = chh * 128 + it * 16 + cc * 4;
        float4 e0 = *(const float4*)&e0p[c];
        size_t o = (((size_t)b * 256 + c) * 64 + y) * 64 + x;
        out0[o]         = e0.x;                    // out0 never depends on decisions
        out0[o + 4096]  = e0.y;
        out0[o + 8192]  = e0.z;
        out0[o + 12288] = e0.w;
        if (!defer) {
            float4 e1 = *(const float4*)&e1p[c];
            float4 q1 = *(const float4*)&q1p[c];
            float4 q2 = *(const float4*)&q2p[c];
            float ef, qf;
            ef = (e1.x + e0.x) * 0.5f; qf = (q1.x + q2.x) * 0.5f; outS[o]         = ef + (qf - ef);
            ef = (e1.y + e0.y) * 0.5f; qf = (q1.y + q2.y) * 0.5f; outS[o + 4096]  = ef + (qf - ef);
            ef = (e1.z + e0.z) * 0.5f; qf = (q1.z + q2.z) * 0.5f; outS[o + 8192]  = ef + (qf - ef);
            ef = (e1.w + e0.w) * 0.5f; qf = (q1.w + q2.w) * 0.5f; outS[o + 12288] = ef + (qf - ef);
        }
    }
}

// ---- fuse stage 2: deferred pixels, full fp64 (3 rows x 512 codes each)
__launch_bounds__(256)
__global__ void fuse2(const float* __restrict__ feat,
                      const float* __restrict__ codebooks,
                      const double* __restrict__ cnd,
                      const int* __restrict__ idx2,
                      const int* __restrict__ dlist, const int* __restrict__ cnt,
                      float* __restrict__ outZ, float* __restrict__ outS) {
    __shared__ double sfd[256];
    __shared__ double rv[4]; __shared__ int rk[4]; __shared__ double rs[4];
    __shared__ double gvmax;
    __shared__ double pRes[3]; __shared__ int kRes[3];
    __shared__ int selS, i2S;
    int tid = threadIdx.x;
    int lane = tid & 63, wave = tid >> 6;
    int n = cnt[1];
    for (int e = blockIdx.x; e < n; e += gridDim.x) {
        int px = dlist[e];
        int b = px >> 12, y = (px >> 6) & 63, x = px & 63;
        int r0 = (b * 64 + y) * 64 + x;
        int r1 = 32768 + (b * 32 + (y >> 1)) * 32 + (x >> 1);
        int r2 = 40960 + (b * 16 + (y >> 2)) * 16 + (x >> 2);
        int rows[3] = {r0, r1, r2};
        for (int s3 = 0; s3 < 3; s3++) {
            sfd[tid] = (double)feat[(size_t)rows[s3] * 256 + tid];
            __syncthreads();
            double vloc[2];
            #pragma unroll
            for (int h = 0; h < 2; h++) {
                int k = h * 256 + tid;
                const float* cp = codebooks + (size_t)k * 256;
                double d0 = 0.0, d1 = 0.0, d2 = 0.0, d3 = 0.0;
                for (int c = 0; c < 256; c += 4) {
                    float4 cv = *(const float4*)&cp[c];
                    d0 = fma((double)cv.x, sfd[c],     d0);
                    d1 = fma((double)cv.y, sfd[c + 1], d1);
                    d2 = fma((double)cv.z, sfd[c + 2], d2);
                    d3 = fma((double)cv.w, sfd[c + 3], d3);
                }
                double dot = (d0 + d1) + (d2 + d3);
                vloc[h] = 2.0 * dot - cnd[k];
            }
            double bv = vloc[0]; int bk = tid;
            if (vloc[1] > bv) { bv = vloc[1]; bk = tid + 256; }
            #pragma unroll
            for (int off = 32; off; off >>= 1) {
                double vo = __shfl_xor(bv, off);
                int ko = __shfl_xor(bk, off);
                if (vo > bv || (vo == bv && ko < bk)) { bv = vo; bk = ko; }
            }
            if (lane == 0) { rv[wave] = bv; rk[wave] = bk; }
            __syncthreads();
            if (tid == 0) {
                double v0 = rv[0]; int K = rk[0];
                #pragma unroll
                for (int w = 1; w < 4; w++)
                    if (rv[w] > v0 || (rv[w] == v0 && rk[w] < K)) { v0 = rv[w]; K = rk[w]; }
                gvmax = v0; kRes[s3] = K;
            }
            __syncthreads();
            double vm = gvmax;
            double s = exp(vloc[0] - vm) + exp(vloc[1] - vm);
            #pragma unroll
            for (int off = 32; off; off >>= 1) s += __shfl_xor(s, off);
            if (lane == 0) rs[wave] = s;
            __syncthreads();
            if (tid == 0) pRes[s3] = 1.0 / (((rs[0] + rs[1]) + rs[2]) + rs[3]);
            __syncthreads();
        }
        if (tid == 0) {
            int sel = 0; double best = pRes[0];
            if (pRes[1] > best) { best = pRes[1]; sel = 1; }
            if (pRes[2] > best) { best = pRes[2]; sel = 2; }
            selS = sel;
            int i2 = idx2[r0];
            i2S = i2;
            size_t zb = (size_t)b * 8192 + (size_t)y * 64 + x;
            outZ[zb] = (float)kRes[sel];
            outZ[zb + 4096] = (float)i2;
        }
        __syncthreads();
        int sel = selS;
        int c = tid;
        float e0 = feat[(size_t)r0 * 256 + c];
        float e1 = feat[(size_t)rows[sel] * 256 + c];
        float q1 = codebooks[(size_t)kRes[sel] * 256 + c];
        float q2 = codebooks[(size_t)(512 + i2S) * 256 + c];
        float ef = (e1 + e0) * 0.5f;
        float qf = (q1 + q2) * 0.5f;
        size_t o = (((size_t)b * 256 + c) * 64 + y) * 64 + x;
        outS[o] = ef + (qf - ef);
        __syncthreads();
    }
}

extern "C" void kernel_launch(void* const* d_in, const int* in_sizes, int n_in,
                              void* d_out, int out_size, void* d_ws, size_t ws_size,
                              hipStream_t stream) {
    (void)in_sizes; (void)n_in; (void)out_size; (void)ws_size;
    const float* image     = (const float*)d_in[0];   // [8,3,256,256]
    const float* conv_w    = (const float*)d_in[1];   // [256,3,4,4]
    const float* conv_b    = (const float*)d_in[2];   // [256]
    const float* codebooks = (const float*)d_in[3];   // [4,512,256]

    float*  ws    = (float*)d_ws;
    float*  feat  = ws + FEAT_OFF;
    float*  parts = ws + PART_OFF;
    float*  prob  = ws + PROB_OFF;
    int*    idx1  = (int*)(ws + IDX1_OFF);
    int*    idx2  = (int*)(ws + IDX2_OFF);
    float*  cnf   = ws + CNF_OFF;
    double* cnd   = (double*)(ws + CND_OFF);
    unsigned short* cbs = (unsigned short*)(ws + CBS_OFF);
    float*  img1  = ws + IMG1_OFF;
    float*  img2  = ws + IMG2_OFF;
    int*    rlist = (int*)(ws + RLIST_OFF);
    int*    dlist = (int*)(ws + DLIST_OFF);
    int*    cnt   = (int*)(ws + CNT_OFF);

    float* out  = (float*)d_out;
    float* out0 = out;
    float* outZ = out + 8388608;
    float* outS = out + 8454144;
    // d_out doubles as scratch for the bf16 feat planes until fuse1 runs;
    // fuse1/fuse2 rewrite every output byte afterwards.
    unsigned short* featbf = (unsigned short*)d_out;

    prep<<<3200, 256, 0, stream>>>(image, codebooks, img1, img2, cnd, cnf, cbs, cnt);
    encode_all<<<1408, 256, 0, stream>>>(image, img1, img2, conv_w, conv_b, feat, featbf);
    match_bulk<<<2368, 256, 0, stream>>>(featbf, cbs, cnf, parts);
    combine_rows<<<296, 256, 0, stream>>>(parts, idx1, idx2, prob, rlist, cnt);
    rescue_exact<<<1024, 256, 0, stream>>>(feat, codebooks, cnd, rlist, cnt, idx1, idx2, prob);
    fuse1<<<1024, 256, 0, stream>>>(feat, prob, idx1, idx2, codebooks, out0, outZ, outS, dlist, cnt);
    fuse2<<<512, 256, 0, stream>>>(feat, codebooks, cnd, idx2, dlist, cnt, outZ, outS);
}